// Round 1
// baseline (2878.938 us; speedup 1.0000x reference)
//
#include <hip/hip_runtime.h>
#include <hip/hip_fp16.h>

// Problem constants
#define NQ   2048      // N_LC == N_TE
#define NB   4         // batch
#define DD   256       // feature dim
#define M1   2049      // NQ + dustbin
#define STR  2064      // padded row stride (fp16 elems for E, bytes for E8, floats for u/v)
#define SINK_ITERS 100
#define PNWG 256       // persistent WGs (64 per batch) — <= guaranteed co-residency (512)
#define PTPB 1024      // 16 waves per WG

typedef __attribute__((ext_vector_type(8))) short short8;
typedef __attribute__((ext_vector_type(4))) float floatx4;
typedef __attribute__((ext_vector_type(2))) float floatx2;

__device__ __forceinline__ unsigned short f2bf(float f) {
  unsigned u = __float_as_uint(f);
  u += 0x7FFF + ((u >> 16) & 1);   // round-to-nearest-even
  return (unsigned short)(u >> 16);
}

// fp32 -> fp8 e5m2 (OCP): e5m2 == top byte of IEEE half, RN
__device__ __forceinline__ unsigned char f2fp8(float f) {
  unsigned short u = __half_as_ushort(__float2half(f));
  return (unsigned char)((u + 0x7F + ((u >> 8) & 1)) >> 8);
}

// swizzled LDS index: pad 1 float per 16 -> lane stride 17 floats (2-way = free)
__device__ __forceinline__ int IDX(int j) { return j + (j >> 4); }

// strip the 8-bit phase tag from a u/v value
__device__ __forceinline__ float untag(float f) {
  return __uint_as_float(__float_as_uint(f) & 0xFFFFFF00u);
}

// ---------------- fp32 -> bf16 convert ----------------
__global__ void k_cvt(const float* __restrict__ src, unsigned short* __restrict__ dst, int n) {
  int i = blockIdx.x * blockDim.x + threadIdx.x;
  if (i < n) dst[i] = f2bf(src[i]);
}

// ---------------- bf16 MFMA GEMM, C = A * B^T (both [rows x K] row-major) ----
// MODE 0: +bias, relu -> bf16          (MLP layer 1)
// MODE 1: +bias       -> bf16          (MLP layer 2)
// MODE 2: *1/16, clamp, exp -> fp16 AND fp8 e5m2   (scores -> E, E8)
// MODE 3: *1/16, clamp, exp -> fp8 e5m2 only       (scores -> ET8)
template<int MODE>
__global__ __launch_bounds__(256, 2)
void k_gemm_bt(const unsigned short* __restrict__ A,
               const unsigned short* __restrict__ Bt,
               void* __restrict__ Out, void* __restrict__ Out8,
               const float* __restrict__ bias,
               int K, long aBatch, long bBatch, long oBatch, int ostride)
{
  __shared__ __align__(16) unsigned short lA[128 * 32];
  __shared__ __align__(16) unsigned short lB[128 * 32];
  const int tid  = threadIdx.x;
  const int lane = tid & 63;
  const int w    = tid >> 6;
  const int wm   = (w >> 1) * 64;
  const int wn   = (w & 1) * 64;
  const long bz  = blockIdx.z;
  const unsigned short* Ab = A  + bz * aBatch + (long)blockIdx.y * 128 * K;
  const unsigned short* Bb = Bt + bz * bBatch + (long)blockIdx.x * 128 * K;

  floatx4 acc[4][4];
  #pragma unroll
  for (int i = 0; i < 4; i++)
    #pragma unroll
    for (int j = 0; j < 4; j++) acc[i][j] = (floatx4){0.f, 0.f, 0.f, 0.f};

  for (int kt = 0; kt < K; kt += 32) {
    __syncthreads();
    #pragma unroll
    for (int s0 = 0; s0 < 512; s0 += 256) {
      int s = s0 + tid;
      int row = s >> 2, part = s & 3;
      ((uint4*)lA)[s] = *(const uint4*)(Ab + (long)row * K + kt + part * 8);
      ((uint4*)lB)[s] = *(const uint4*)(Bb + (long)row * K + kt + part * 8);
    }
    __syncthreads();
    const int kq = (lane >> 4) * 8;
    const int rl = lane & 15;
    short8 af[4], bf[4];
    #pragma unroll
    for (int t = 0; t < 4; t++) {
      af[t] = *(const short8*)(lA + (wm + t * 16 + rl) * 32 + kq);
      bf[t] = *(const short8*)(lB + (wn + t * 16 + rl) * 32 + kq);
    }
    #pragma unroll
    for (int i = 0; i < 4; i++)
      #pragma unroll
      for (int j = 0; j < 4; j++)
        acc[i][j] = __builtin_amdgcn_mfma_f32_16x16x32_bf16(af[i], bf[j], acc[i][j], 0, 0, 0);
  }

  // epilogue — C/D layout: col = lane&15, row = (lane>>4)*4 + reg
  const int cl = lane & 15, qd = lane >> 4;
  #pragma unroll
  for (int i = 0; i < 4; i++)
    #pragma unroll
    for (int j = 0; j < 4; j++) {
      const int col = blockIdx.x * 128 + wn + j * 16 + cl;
      const float bcol = (MODE >= 2) ? 0.f : bias[col];
      #pragma unroll
      for (int r = 0; r < 4; r++) {
        const long row = (long)blockIdx.y * 128 + wm + i * 16 + qd * 4 + r;
        float v = acc[i][j][r];
        if (MODE == 0) {
          v += bcol; v = v > 0.f ? v : 0.f;
          ((unsigned short*)Out)[bz * oBatch + row * ostride + col] = f2bf(v);
        } else if (MODE == 1) {
          v += bcol;
          ((unsigned short*)Out)[bz * oBatch + row * ostride + col] = f2bf(v);
        } else {
          v *= 0.0625f;                       // 1/sqrt(256)
          v = fminf(fmaxf(v, -15.f), 10.9f);  // e^10.9 = 54k < e5m2 max 57344
          float e = __expf(v);
          const long idx = bz * oBatch + row * ostride + col;
          if (MODE == 2) ((__half*)Out)[idx] = __float2half(e);
          ((unsigned char*)Out8)[idx] = f2fp8(e);
        }
      }
    }
}

// ---------------- fill dustbin row/col + zero padding of fp16 E --------------
__global__ void k_fill(__half* __restrict__ E, const float* __restrict__ alphaPtr) {
  const float ea = __expf(*alphaPtr);
  const int idx = blockIdx.x * blockDim.x + threadIdx.x;
  const int n1 = NB * NQ * 16;  // rows 0..2047, cols 2048..2063
  if (idx < n1) {
    int b = idx / (NQ * 16);
    int rr = idx - b * NQ * 16;
    int i = rr >> 4;
    int j = 2048 + (rr & 15);
    E[((long)b * M1 + i) * STR + j] = (j == 2048) ? __float2half(ea) : __float2half(0.f);
  } else {
    int k = idx - n1;             // dustbin row: NB * STR entries
    if (k < NB * STR) {
      int b = k / STR;
      int j = k - b * STR;
      E[((long)b * M1 + 2048) * STR + j] = (j <= 2048) ? __float2half(ea) : __float2half(0.f);
    }
  }
}

// ---------------- init: ev = 1.0 (tag 0 == phase-0 expectation),
//                        eu = 0.0 (tag 0, even; eu expectations are odd) -----
__global__ void k_init(float* __restrict__ v, float* __restrict__ u, int n) {
  int i = blockIdx.x * blockDim.x + threadIdx.x;
  if (i < n) { v[i] = 1.0f; u[i] = 0.0f; }
}

// ---------------- agent-scope relaxed helpers (NO cache invalidates) ---------
// Tag protocol: low 8 mantissa bits of every u/v value carry the phase tag.
// Phase p (0..199) reads vin expecting tag p, writes vout with tag p+1.
// Tags never wrap (200 < 256) -> a matching tag can ONLY be the current value.
// Tag and value share one 32-bit word -> no ordering/fence needed at all.
__device__ __forceinline__ void st_tag(float* p, float v, unsigned tag) {
  unsigned b = (__float_as_uint(v) & 0xFFFFFF00u) | tag;
  __hip_atomic_store((unsigned*)p, b, __ATOMIC_RELAXED, __HIP_MEMORY_SCOPE_AGENT);
}
__device__ __forceinline__ unsigned ld_u32_agent(const unsigned* p) {
  return __hip_atomic_load(p, __ATOMIC_RELAXED, __HIP_MEMORY_SCOPE_AGENT);
}
__device__ __forceinline__ unsigned poll_tag(const unsigned* q, unsigned bits, unsigned expect) {
  while ((bits & 0xFFu) != expect) {
    __builtin_amdgcn_s_sleep(1);
    bits = ld_u32_agent(q);
  }
  return bits;
}

__device__ __forceinline__ float wave_sum(float s) {
  #pragma unroll
  for (int o = 32; o; o >>= 1) s += __shfl_xor(s, o);
  return s;
}

// dot of 16 fp8(e5m2) values with 16 fp32 weights at wp[0..15]
__device__ __forceinline__ float dot16f8(uint4 hv, const float* wp) {
  const unsigned* u = (const unsigned*)&hv;
  float s = 0.f;
#if __has_builtin(__builtin_amdgcn_cvt_pk_f32_bf8)
  #pragma unroll
  for (int q = 0; q < 4; q++) {
    floatx2 lo = __builtin_amdgcn_cvt_pk_f32_bf8((int)u[q], false);
    floatx2 hi = __builtin_amdgcn_cvt_pk_f32_bf8((int)u[q], true);
    s += lo.x * wp[q * 4 + 0] + lo.y * wp[q * 4 + 1]
       + hi.x * wp[q * 4 + 2] + hi.y * wp[q * 4 + 3];
  }
#else
  const unsigned char* p = (const unsigned char*)&hv;
  #pragma unroll
  for (int t = 0; t < 16; t++) {
    unsigned short h = (unsigned short)p[t] << 8;
    s += __half2float(*reinterpret_cast<__half*>(&h)) * wp[t];
  }
#endif
  return s;
}

// ---------------- persistent Sinkhorn, plain launch (NOT cooperative) --------
// Grid 256 WGs x 1024 thr. Co-residency guaranteed: __launch_bounds__(1024,4)
// => >=16 waves/CU => >=1 WG/CU capacity (256) >= grid (256).
// NO grid barrier at all: every u/v slot is self-validating via its embedded
// 8-bit phase tag. Runahead is self-limiting (phase p+1 needs ALL tag-p slots;
// a WG publishes only after its whole WG finished consuming the prior vector).
// Score rows are hoisted into registers ONCE (32 VGPRs) — the inner loop reads
// zero score-matrix bytes. Fixed 100 iterations (tripwire-safe).
__global__ __launch_bounds__(PTPB, 4)
void k_sink(const unsigned char* __restrict__ E8, const unsigned char* __restrict__ ET8,
            float* __restrict__ eu, float* __restrict__ ev,
            const float* __restrict__ alphaPtr)
{
  __shared__ __align__(16) float sv[2200];   // swizzled vector (2064 + pads)
  const int tid  = threadIdx.x;
  const int wg   = blockIdx.x;
  const int b    = wg >> 6;          // batch 0..3
  const int g    = wg & 63;          // group within batch
  const int wv   = tid >> 6;         // wave 0..15
  const int lane = tid & 63;
  const int r0   = (g * 16 + wv) * 2;   // rows r0, r0+1 in [0, 2048)
  const float ea = __expf(alphaPtr[0]);
  const unsigned char* E8r  = E8  + ((long)b * M1 + r0) * STR;
  const unsigned char* ET8r = ET8 + ((long)b * M1 + r0) * STR;
  float* ub = eu + b * STR;
  float* vb = ev + b * STR;
  const bool dustwave = (g == 63) && (wv == 15);

  // hoist all four fp8 rows (2 per matrix, 16 B/lane/chunk) into registers
  const uint4 rA0 = *(const uint4*)(E8r  +               lane * 16);
  const uint4 rA1 = *(const uint4*)(E8r  + 1024 +        lane * 16);
  const uint4 rA2 = *(const uint4*)(E8r  + STR  +        lane * 16);
  const uint4 rA3 = *(const uint4*)(E8r  + STR  + 1024 + lane * 16);
  const uint4 rB0 = *(const uint4*)(ET8r +               lane * 16);
  const uint4 rB1 = *(const uint4*)(ET8r + 1024 +        lane * 16);
  const uint4 rB2 = *(const uint4*)(ET8r + STR  +        lane * 16);
  const uint4 rB3 = *(const uint4*)(ET8r + STR  + 1024 + lane * 16);

  const float* w0 = sv + lane * 17;          // IDX(lane*16)
  const float* w1 = sv + 1088 + lane * 17;   // IDX(1024 + lane*16)
  const int j0 = tid;                        // [0, 1024)
  const int j1 = tid + 1024;                 // [1024, 2048)

  auto phase = [&](const uint4& c0, const uint4& c1, const uint4& c2, const uint4& c3,
                   const float* vin, float* vout, unsigned p) {
    const unsigned expect = p & 0xFFu;
    const unsigned newtag = (p + 1) & 0xFFu;

    // stage vin -> swizzled LDS, polling per-slot tags (issue both loads first)
    const unsigned* q0 = (const unsigned*)(vin + j0);
    const unsigned* q1 = (const unsigned*)(vin + j1);
    unsigned b0 = ld_u32_agent(q0);
    unsigned b1 = ld_u32_agent(q1);
    b0 = poll_tag(q0, b0, expect);
    b1 = poll_tag(q1, b1, expect);
    sv[IDX(j0)] = __uint_as_float(b0 & 0xFFFFFF00u);
    sv[IDX(j1)] = __uint_as_float(b1 & 0xFFFFFF00u);
    if (tid == 0) {
      const unsigned* q2 = (const unsigned*)(vin + 2048);
      unsigned b2 = poll_tag(q2, ld_u32_agent(q2), expect);
      sv[IDX(2048)] = __uint_as_float(b2 & 0xFFFFFF00u);
    }
    __syncthreads();

    // two rows per wave, all operand bytes already in registers
    float d0 = dot16f8(c0, w0) + dot16f8(c1, w1);
    float d1 = dot16f8(c2, w0) + dot16f8(c3, w1);
    d0 = wave_sum(d0);
    d1 = wave_sum(d1);
    if (lane == 0) {
      const float wd = ea * sv[IDX(2048)];     // dustbin column (value == ea)
      st_tag(vout + r0,     (1.f / 4096.f) / (d0 + wd), newtag);
      st_tag(vout + r0 + 1, (1.f / 4096.f) / (d1 + wd), newtag);
    }

    // dustbin row analytic: vout[2048] = 0.5 / (ea * sum(vin))
    if (dustwave) {
      float s = 0.f;
      #pragma unroll
      for (int t = 0; t < 16; t++) s += w0[t] + w1[t];
      s = wave_sum(s);
      if (lane == 0) st_tag(vout + 2048, 0.5f / (ea * (s + sv[IDX(2048)])), newtag);
    }
    __syncthreads();   // protect sv from next phase's staging
  };

  for (int i = 0; i < SINK_ITERS; ++i) {
    phase(rA0, rA1, rA2, rA3, vb, ub, 2 * i);
    phase(rB0, rB1, rB2, rB3, ub, vb, 2 * i + 1);
  }
}

// ---------------- finalize: out = E * eu * ev * 4096 (fp16 E) ----------------
__global__ void k_final(const __half* __restrict__ E, const float* __restrict__ eu,
                        const float* __restrict__ ev, float* __restrict__ out) {
  const int wv = blockIdx.x;      // NB * M1 rows
  const int b = wv / M1;
  const int i = wv - b * M1;
  const __half* R = E + ((long)b * M1 + i) * STR;
  const float ui = untag(eu[b * STR + i]) * 4096.f;   // * exp(-norm)
  const float* evb = ev + b * STR;
  float* orow = out + ((long)b * M1 + i) * M1;
  for (int j = threadIdx.x; j < M1; j += blockDim.x)
    orow[j] = __half2float(R[j]) * ui * untag(evb[j]);
}

// ---------------- launch -----------------------------------------------------
extern "C" void kernel_launch(void* const* d_in, const int* in_sizes, int n_in,
                              void* d_out, int out_size, void* d_ws, size_t ws_size,
                              hipStream_t stream) {
  const float* x_lc  = (const float*)d_in[0];
  const float* x_te  = (const float*)d_in[1];
  const float* W1_lc = (const float*)d_in[2];
  const float* b1_lc = (const float*)d_in[3];
  const float* W2_lc = (const float*)d_in[4];
  const float* b2_lc = (const float*)d_in[5];
  const float* W1_te = (const float*)d_in[6];
  const float* b1_te = (const float*)d_in[7];
  const float* W2_te = (const float*)d_in[8];
  const float* b2_te = (const float*)d_in[9];
  const float* alpha = (const float*)d_in[10];

  char* ws = (char*)d_ws;
  unsigned short* Xlc = (unsigned short*)(ws + 0);          //  4 MB
  unsigned short* Xte = (unsigned short*)(ws + 4194304);    //  4 MB
  unsigned short* Wb  = (unsigned short*)(ws + 8388608);    //  0.5 MB
  unsigned short* H   = (unsigned short*)(ws + 8912896);    //  4 MB
  unsigned short* F1  = (unsigned short*)(ws + 13107200);   //  4 MB
  unsigned short* F2  = (unsigned short*)(ws + 17301504);   //  4 MB
  __half* E  = (__half*)(ws + 21495808);                    // 33.83 MB fp16 (final)
  unsigned char* E8  = (unsigned char*)(ws + 55328896);     // 16.92 MB fp8 (sweep)
  unsigned char* ET8 = (unsigned char*)(ws + 72245440);     // 16.92 MB fp8 (sweep)
  float* eu  = (float*)(ws + 89161984);                     // 4 x 2064 f32
  float* ev  = (float*)(ws + 89195008);                     // 4 x 2064 f32

  const int NX = NB * NQ * DD;   // 2097152
  const int NW = DD * DD;        // 65536

  k_cvt<<<(NX + 255) / 256, 256, 0, stream>>>(x_lc, Xlc, NX);
  k_cvt<<<(NX + 255) / 256, 256, 0, stream>>>(x_te, Xte, NX);
  k_cvt<<<(NW + 255) / 256, 256, 0, stream>>>(W1_lc, Wb,           NW);
  k_cvt<<<(NW + 255) / 256, 256, 0, stream>>>(W2_lc, Wb + 65536,   NW);
  k_cvt<<<(NW + 255) / 256, 256, 0, stream>>>(W1_te, Wb + 131072,  NW);
  k_cvt<<<(NW + 255) / 256, 256, 0, stream>>>(W2_te, Wb + 196608,  NW);

  // MLPs (rows flattened over batch: M = 8192, N = 256, K = 256)
  k_gemm_bt<0><<<dim3(2, 64, 1), 256, 0, stream>>>(Xlc, Wb,          H,  nullptr, b1_lc, DD, 0, 0, 0, DD);
  k_gemm_bt<1><<<dim3(2, 64, 1), 256, 0, stream>>>(H,   Wb + 65536,  F1, nullptr, b2_lc, DD, 0, 0, 0, DD);
  k_gemm_bt<0><<<dim3(2, 64, 1), 256, 0, stream>>>(Xte, Wb + 131072, H,  nullptr, b1_te, DD, 0, 0, 0, DD);
  k_gemm_bt<1><<<dim3(2, 64, 1), 256, 0, stream>>>(H,   Wb + 196608, F2, nullptr, b2_te, DD, 0, 0, 0, DD);

  // scores -> E (fp16+fp8) and ET (fp8 only), per batch
  const long ab = (long)NQ * DD;        // 524288
  const long ob = (long)M1 * STR;       // 4229136 (elems for fp16, bytes for fp8)
  k_gemm_bt<2><<<dim3(16, 16, NB), 256, 0, stream>>>(F1, F2, E,  E8,  nullptr, DD, ab, ab, ob, STR);
  k_gemm_bt<3><<<dim3(16, 16, NB), 256, 0, stream>>>(F2, F1, nullptr, ET8, nullptr, DD, ab, ab, ob, STR);

  // dustbin row/col + padding (fp16 E only; fp8 dustbin handled analytically)
  const int nfill = NB * NQ * 16 + NB * STR;  // 139328
  k_fill<<<(nfill + 255) / 256, 256, 0, stream>>>(E, alpha);

  // ev = 1 (tag 0), eu = 0 (tag 0, never matches odd eu expectations)
  k_init<<<(NB * STR + 255) / 256, 256, 0, stream>>>(ev, eu, NB * STR);

  // persistent Sinkhorn: ONE plain launch, fixed 100 iterations, no barrier
  k_sink<<<PNWG, PTPB, 0, stream>>>(E8, ET8, eu, ev, alpha);

  // out = E * eu * ev * (m+n)
  k_final<<<NB * M1, 256, 0, stream>>>(E, eu, ev, (float*)d_out);
}

// Round 2
// 2525.669 us; speedup vs baseline: 1.1399x; 1.1399x over previous
//
#include <hip/hip_runtime.h>
#include <hip/hip_fp16.h>

// Problem constants
#define NQ   2048      // N_LC == N_TE
#define NB   4         // batch
#define DD   256       // feature dim
#define M1   2049      // NQ + dustbin
#define STR  2064      // padded row stride (fp16 elems for E, bytes for E8, floats for u/v)
#define SINK_ITERS 100
#define PNWG 256       // persistent WGs (64 per batch) — <= guaranteed co-residency (256, 1/CU)
#define PTPB 1024      // 16 waves per WG

typedef __attribute__((ext_vector_type(8))) short short8;
typedef __attribute__((ext_vector_type(4))) float floatx4;
typedef __attribute__((ext_vector_type(2))) float floatx2;

__device__ __forceinline__ unsigned short f2bf(float f) {
  unsigned u = __float_as_uint(f);
  u += 0x7FFF + ((u >> 16) & 1);   // round-to-nearest-even
  return (unsigned short)(u >> 16);
}

// fp32 -> fp8 e5m2 (OCP): e5m2 == top byte of IEEE half, RN
__device__ __forceinline__ unsigned char f2fp8(float f) {
  unsigned short u = __half_as_ushort(__float2half(f));
  return (unsigned char)((u + 0x7F + ((u >> 8) & 1)) >> 8);
}

// swizzled LDS index: pad 1 float per 16 -> lane stride 17 floats (2-way = free)
__device__ __forceinline__ int IDX(int j) { return j + (j >> 4); }

// ---------------- fp32 -> bf16 convert ----------------
__global__ void k_cvt(const float* __restrict__ src, unsigned short* __restrict__ dst, int n) {
  int i = blockIdx.x * blockDim.x + threadIdx.x;
  if (i < n) dst[i] = f2bf(src[i]);
}

// ---------------- bf16 MFMA GEMM, C = A * B^T (both [rows x K] row-major) ----
// MODE 0: +bias, relu -> bf16          (MLP layer 1)
// MODE 1: +bias       -> bf16          (MLP layer 2)
// MODE 2: *1/16, clamp, exp -> fp16 AND fp8 e5m2   (scores -> E, E8)
// MODE 3: *1/16, clamp, exp -> fp8 e5m2 only       (scores -> ET8)
template<int MODE>
__global__ __launch_bounds__(256, 2)
void k_gemm_bt(const unsigned short* __restrict__ A,
               const unsigned short* __restrict__ Bt,
               void* __restrict__ Out, void* __restrict__ Out8,
               const float* __restrict__ bias,
               int K, long aBatch, long bBatch, long oBatch, int ostride)
{
  __shared__ __align__(16) unsigned short lA[128 * 32];
  __shared__ __align__(16) unsigned short lB[128 * 32];
  const int tid  = threadIdx.x;
  const int lane = tid & 63;
  const int w    = tid >> 6;
  const int wm   = (w >> 1) * 64;
  const int wn   = (w & 1) * 64;
  const long bz  = blockIdx.z;
  const unsigned short* Ab = A  + bz * aBatch + (long)blockIdx.y * 128 * K;
  const unsigned short* Bb = Bt + bz * bBatch + (long)blockIdx.x * 128 * K;

  floatx4 acc[4][4];
  #pragma unroll
  for (int i = 0; i < 4; i++)
    #pragma unroll
    for (int j = 0; j < 4; j++) acc[i][j] = (floatx4){0.f, 0.f, 0.f, 0.f};

  for (int kt = 0; kt < K; kt += 32) {
    __syncthreads();
    #pragma unroll
    for (int s0 = 0; s0 < 512; s0 += 256) {
      int s = s0 + tid;
      int row = s >> 2, part = s & 3;
      ((uint4*)lA)[s] = *(const uint4*)(Ab + (long)row * K + kt + part * 8);
      ((uint4*)lB)[s] = *(const uint4*)(Bb + (long)row * K + kt + part * 8);
    }
    __syncthreads();
    const int kq = (lane >> 4) * 8;
    const int rl = lane & 15;
    short8 af[4], bf[4];
    #pragma unroll
    for (int t = 0; t < 4; t++) {
      af[t] = *(const short8*)(lA + (wm + t * 16 + rl) * 32 + kq);
      bf[t] = *(const short8*)(lB + (wn + t * 16 + rl) * 32 + kq);
    }
    #pragma unroll
    for (int i = 0; i < 4; i++)
      #pragma unroll
      for (int j = 0; j < 4; j++)
        acc[i][j] = __builtin_amdgcn_mfma_f32_16x16x32_bf16(af[i], bf[j], acc[i][j], 0, 0, 0);
  }

  // epilogue — C/D layout: col = lane&15, row = (lane>>4)*4 + reg
  const int cl = lane & 15, qd = lane >> 4;
  #pragma unroll
  for (int i = 0; i < 4; i++)
    #pragma unroll
    for (int j = 0; j < 4; j++) {
      const int col = blockIdx.x * 128 + wn + j * 16 + cl;
      const float bcol = (MODE >= 2) ? 0.f : bias[col];
      #pragma unroll
      for (int r = 0; r < 4; r++) {
        const long row = (long)blockIdx.y * 128 + wm + i * 16 + qd * 4 + r;
        float v = acc[i][j][r];
        if (MODE == 0) {
          v += bcol; v = v > 0.f ? v : 0.f;
          ((unsigned short*)Out)[bz * oBatch + row * ostride + col] = f2bf(v);
        } else if (MODE == 1) {
          v += bcol;
          ((unsigned short*)Out)[bz * oBatch + row * ostride + col] = f2bf(v);
        } else {
          v *= 0.0625f;                       // 1/sqrt(256)
          v = fminf(fmaxf(v, -15.f), 10.9f);  // e^10.9 = 54k < e5m2 max 57344
          float e = __expf(v);
          const long idx = bz * oBatch + row * ostride + col;
          if (MODE == 2) ((__half*)Out)[idx] = __float2half(e);
          ((unsigned char*)Out8)[idx] = f2fp8(e);
        }
      }
    }
}

// ---------------- fill dustbin row/col + zero padding of fp16 E --------------
__global__ void k_fill(__half* __restrict__ E, const float* __restrict__ alphaPtr) {
  const float ea = __expf(*alphaPtr);
  const int idx = blockIdx.x * blockDim.x + threadIdx.x;
  const int n1 = NB * NQ * 16;  // rows 0..2047, cols 2048..2063
  if (idx < n1) {
    int b = idx / (NQ * 16);
    int rr = idx - b * NQ * 16;
    int i = rr >> 4;
    int j = 2048 + (rr & 15);
    E[((long)b * M1 + i) * STR + j] = (j == 2048) ? __float2half(ea) : __float2half(0.f);
  } else {
    int k = idx - n1;             // dustbin row: NB * STR entries
    if (k < NB * STR) {
      int b = k / STR;
      int j = k - b * STR;
      E[((long)b * M1 + 2048) * STR + j] = (j <= 2048) ? __float2half(ea) : __float2half(0.f);
    }
  }
}

// ---------------- init ev = 1, zero barrier state ----------------------------
__global__ void k_init(float* __restrict__ v, int n, unsigned* __restrict__ bar) {
  int i = blockIdx.x * blockDim.x + threadIdx.x;
  if (i < n) v[i] = 1.0f;
  if (i < 2048) bar[i] = 0u;   // barrier counters (only 4 used, 32-uint spaced)
}

// ---------------- agent-scope relaxed helpers (NO cache invalidates) ---------
__device__ __forceinline__ void st_agent(float* p, float v) {
  __hip_atomic_store(p, v, __ATOMIC_RELAXED, __HIP_MEMORY_SCOPE_AGENT);
}
__device__ __forceinline__ float ld_agent(const float* p) {
  return __hip_atomic_load(p, __ATOMIC_RELAXED, __HIP_MEMORY_SCOPE_AGENT);
}
__device__ __forceinline__ unsigned ld_u32_agent(const unsigned* p) {
  return __hip_atomic_load(p, __ATOMIC_RELAXED, __HIP_MEMORY_SCOPE_AGENT);
}

__device__ __forceinline__ float wave_sum(float s) {
  #pragma unroll
  for (int o = 32; o; o >>= 1) s += __shfl_xor(s, o);
  return s;
}

// dot of 16 fp8(e5m2) values with 16 fp32 weights at wp[0..15]
__device__ __forceinline__ float dot16f8(uint4 hv, const float* wp) {
  const unsigned* u = (const unsigned*)&hv;
  float s = 0.f;
#if __has_builtin(__builtin_amdgcn_cvt_pk_f32_bf8)
  #pragma unroll
  for (int q = 0; q < 4; q++) {
    floatx2 lo = __builtin_amdgcn_cvt_pk_f32_bf8((int)u[q], false);
    floatx2 hi = __builtin_amdgcn_cvt_pk_f32_bf8((int)u[q], true);
    s += lo.x * wp[q * 4 + 0] + lo.y * wp[q * 4 + 1]
       + hi.x * wp[q * 4 + 2] + hi.y * wp[q * 4 + 3];
  }
#else
  const unsigned char* p = (const unsigned char*)&hv;
  #pragma unroll
  for (int t = 0; t < 16; t++) {
    unsigned short h = (unsigned short)p[t] << 8;
    s += __half2float(*reinterpret_cast<__half*>(&h)) * wp[t];
  }
#endif
  return s;
}

// ---------------- persistent Sinkhorn, plain launch (NOT cooperative) --------
// Grid 256 WGs x 1024 thr. Co-residency guaranteed: __launch_bounds__(1024,4)
// => >=16 waves/CU => >=1 WG/CU => capacity (256) >= grid (256); barriers
// cannot deadlock. 64 WGs per batch.
//
// Sync = ONE monotone flat counter per batch (R2 design):
//   each WG's tid0: fetch_add(cnt,1) then poll cnt until >= 64*phase.
// Correct because the counter is monotone: cnt can only reach 64*(p+1) after
// every WG arrived p+1 times (a WG arrives for p+1 only after passing p).
// Exactly 256 pollers device-wide on 4 words (vs R1's 1M pollers on 8K words
// — the EA poll storm that caused the 3x regression). Critical path per
// barrier: last add -> pollers' in-flight load observes it (~1 LLC hop).
//
// Score rows are hoisted into registers ONCE (32 VGPRs) — the inner loop
// reads zero score-matrix bytes (R1's one validated win).
// u/v traffic via agent-scope relaxed atomics (LLC-coherent, NO L2
// invalidates). Fixed 100 iterations — identical work every call.
__global__ __launch_bounds__(PTPB, 4)
void k_sink(const unsigned char* __restrict__ E8, const unsigned char* __restrict__ ET8,
            float* __restrict__ eu, float* __restrict__ ev,
            const float* __restrict__ alphaPtr, unsigned* __restrict__ bar)
{
  __shared__ __align__(16) float sv[2200];   // swizzled vector (2064 + pads)
  const int tid  = threadIdx.x;
  const int wg   = blockIdx.x;
  const int b    = wg >> 6;          // batch 0..3
  const int g    = wg & 63;          // group within batch
  const int wv   = tid >> 6;         // wave 0..15
  const int lane = tid & 63;
  const int r0   = (g * 16 + wv) * 2;   // rows r0, r0+1 in [0, 2048)
  const float ea = __expf(alphaPtr[0]);
  const unsigned char* E8r  = E8  + ((long)b * M1 + r0) * STR;
  const unsigned char* ET8r = ET8 + ((long)b * M1 + r0) * STR;
  float* ub = eu + b * STR;
  float* vb = ev + b * STR;
  unsigned* cnt = bar + b * 32;      // per-batch counter, 128 B apart
  const bool dustwave = (g == 63) && (wv == 15);

  // hoist all four fp8 rows (2 per matrix, 16 B/lane/chunk) into registers
  const uint4 rA0 = *(const uint4*)(E8r  +               lane * 16);
  const uint4 rA1 = *(const uint4*)(E8r  + 1024 +        lane * 16);
  const uint4 rA2 = *(const uint4*)(E8r  + STR  +        lane * 16);
  const uint4 rA3 = *(const uint4*)(E8r  + STR  + 1024 + lane * 16);
  const uint4 rB0 = *(const uint4*)(ET8r +               lane * 16);
  const uint4 rB1 = *(const uint4*)(ET8r + 1024 +        lane * 16);
  const uint4 rB2 = *(const uint4*)(ET8r + STR  +        lane * 16);
  const uint4 rB3 = *(const uint4*)(ET8r + STR  + 1024 + lane * 16);

  const float* w0 = sv + lane * 17;          // IDX(lane*16)
  const float* w1 = sv + 1088 + lane * 17;   // IDX(1024 + lane*16)
  const int j0 = tid;                        // [0, 1024)
  const int j1 = tid + 1024;                 // [1024, 2048)

  unsigned target = 0;
  auto phase = [&](const uint4& c0, const uint4& c1, const uint4& c2, const uint4& c3,
                   const float* vin, float* vout) {
    // stage vin -> swizzled LDS (both loads issued before either is consumed)
    float s0 = ld_agent(vin + j0);
    float s1 = ld_agent(vin + j1);
    sv[IDX(j0)] = s0;
    sv[IDX(j1)] = s1;
    if (tid == 0) sv[IDX(2048)] = ld_agent(vin + 2048);
    __syncthreads();

    // two rows per wave, all operand bytes already in registers
    float d0 = dot16f8(c0, w0) + dot16f8(c1, w1);
    float d1 = dot16f8(c2, w0) + dot16f8(c3, w1);
    d0 = wave_sum(d0);
    d1 = wave_sum(d1);
    if (lane == 0) {
      const float wd = ea * sv[IDX(2048)];     // dustbin column (value == ea)
      st_agent(vout + r0,     (1.f / 4096.f) / (d0 + wd));
      st_agent(vout + r0 + 1, (1.f / 4096.f) / (d1 + wd));
    }

    // dustbin row analytic: vout[2048] = 0.5 / (ea * sum(vin))
    if (dustwave) {
      float s = 0.f;
      #pragma unroll
      for (int t = 0; t < 16; t++) s += w0[t] + w1[t];
      s = wave_sum(s);
      if (lane == 0) st_agent(vout + 2048, 0.5f / (ea * (s + sv[IDX(2048)])));
    }

    // ---- per-batch flat-counter barrier (relaxed, no cache maintenance) ----
    target += 64;
    __syncthreads();   // drains each wave's vmcnt: this WG's stores are at LLC
    if (tid == 0) {
      __hip_atomic_fetch_add(cnt, 1u, __ATOMIC_RELAXED, __HIP_MEMORY_SCOPE_AGENT);
      while (ld_u32_agent(cnt) < target)
        __builtin_amdgcn_s_sleep(1);
    }
    __syncthreads();
  };

  for (int i = 0; i < SINK_ITERS; ++i) {
    phase(rA0, rA1, rA2, rA3, vb, ub);
    phase(rB0, rB1, rB2, rB3, ub, vb);
  }
}

// ---------------- finalize: out = E * eu * ev * 4096 (fp16 E) ----------------
__global__ void k_final(const __half* __restrict__ E, const float* __restrict__ eu,
                        const float* __restrict__ ev, float* __restrict__ out) {
  const int wv = blockIdx.x;      // NB * M1 rows
  const int b = wv / M1;
  const int i = wv - b * M1;
  const __half* R = E + ((long)b * M1 + i) * STR;
  const float ui = eu[b * STR + i] * 4096.f;   // * exp(-norm)
  const float* evb = ev + b * STR;
  float* orow = out + ((long)b * M1 + i) * M1;
  for (int j = threadIdx.x; j < M1; j += blockDim.x)
    orow[j] = __half2float(R[j]) * ui * evb[j];
}

// ---------------- launch -----------------------------------------------------
extern "C" void kernel_launch(void* const* d_in, const int* in_sizes, int n_in,
                              void* d_out, int out_size, void* d_ws, size_t ws_size,
                              hipStream_t stream) {
  const float* x_lc  = (const float*)d_in[0];
  const float* x_te  = (const float*)d_in[1];
  const float* W1_lc = (const float*)d_in[2];
  const float* b1_lc = (const float*)d_in[3];
  const float* W2_lc = (const float*)d_in[4];
  const float* b2_lc = (const float*)d_in[5];
  const float* W1_te = (const float*)d_in[6];
  const float* b1_te = (const float*)d_in[7];
  const float* W2_te = (const float*)d_in[8];
  const float* b2_te = (const float*)d_in[9];
  const float* alpha = (const float*)d_in[10];

  char* ws = (char*)d_ws;
  unsigned short* Xlc = (unsigned short*)(ws + 0);          //  4 MB
  unsigned short* Xte = (unsigned short*)(ws + 4194304);    //  4 MB
  unsigned short* Wb  = (unsigned short*)(ws + 8388608);    //  0.5 MB
  unsigned short* H   = (unsigned short*)(ws + 8912896);    //  4 MB
  unsigned short* F1  = (unsigned short*)(ws + 13107200);   //  4 MB
  unsigned short* F2  = (unsigned short*)(ws + 17301504);   //  4 MB
  __half* E  = (__half*)(ws + 21495808);                    // 33.83 MB fp16 (final)
  unsigned char* E8  = (unsigned char*)(ws + 55328896);     // 16.92 MB fp8 (sweep)
  unsigned char* ET8 = (unsigned char*)(ws + 72245440);     // 16.92 MB fp8 (sweep)
  float* eu  = (float*)(ws + 89161984);                     // 4 x 2064 f32
  float* ev  = (float*)(ws + 89195008);                     // 4 x 2064 f32
  unsigned* bar = (unsigned*)(ws + 89228032);               // 8 KB barrier state

  const int NX = NB * NQ * DD;   // 2097152
  const int NW = DD * DD;        // 65536

  k_cvt<<<(NX + 255) / 256, 256, 0, stream>>>(x_lc, Xlc, NX);
  k_cvt<<<(NX + 255) / 256, 256, 0, stream>>>(x_te, Xte, NX);
  k_cvt<<<(NW + 255) / 256, 256, 0, stream>>>(W1_lc, Wb,           NW);
  k_cvt<<<(NW + 255) / 256, 256, 0, stream>>>(W2_lc, Wb + 65536,   NW);
  k_cvt<<<(NW + 255) / 256, 256, 0, stream>>>(W1_te, Wb + 131072,  NW);
  k_cvt<<<(NW + 255) / 256, 256, 0, stream>>>(W2_te, Wb + 196608,  NW);

  // MLPs (rows flattened over batch: M = 8192, N = 256, K = 256)
  k_gemm_bt<0><<<dim3(2, 64, 1), 256, 0, stream>>>(Xlc, Wb,          H,  nullptr, b1_lc, DD, 0, 0, 0, DD);
  k_gemm_bt<1><<<dim3(2, 64, 1), 256, 0, stream>>>(H,   Wb + 65536,  F1, nullptr, b2_lc, DD, 0, 0, 0, DD);
  k_gemm_bt<0><<<dim3(2, 64, 1), 256, 0, stream>>>(Xte, Wb + 131072, H,  nullptr, b1_te, DD, 0, 0, 0, DD);
  k_gemm_bt<1><<<dim3(2, 64, 1), 256, 0, stream>>>(H,   Wb + 196608, F2, nullptr, b2_te, DD, 0, 0, 0, DD);

  // scores -> E (fp16+fp8) and ET (fp8 only), per batch
  const long ab = (long)NQ * DD;        // 524288
  const long ob = (long)M1 * STR;       // 4229136 (elems for fp16, bytes for fp8)
  k_gemm_bt<2><<<dim3(16, 16, NB), 256, 0, stream>>>(F1, F2, E,  E8,  nullptr, DD, ab, ab, ob, STR);
  k_gemm_bt<3><<<dim3(16, 16, NB), 256, 0, stream>>>(F2, F1, nullptr, ET8, nullptr, DD, ab, ab, ob, STR);

  // dustbin row/col + padding (fp16 E only; fp8 dustbin handled analytically)
  const int nfill = NB * NQ * 16 + NB * STR;  // 139328
  k_fill<<<(nfill + 255) / 256, 256, 0, stream>>>(E, alpha);

  // ev = 1, barrier = 0
  k_init<<<(NB * STR + 255) / 256, 256, 0, stream>>>(ev, NB * STR, bar);

  // persistent Sinkhorn: ONE plain launch, fixed 100 iterations
  k_sink<<<PNWG, PTPB, 0, stream>>>(E8, ET8, eu, ev, alpha, bar);

  // out = E * eu * ev * (m+n)
  k_final<<<NB * M1, 256, 0, stream>>>(E, eu, ev, (float*)d_out);
}

// Round 3
// 2476.111 us; speedup vs baseline: 1.1627x; 1.0200x over previous
//
#include <hip/hip_runtime.h>
#include <hip/hip_fp16.h>

// Problem constants
#define NQ   2048      // N_LC == N_TE
#define NB   4         // batch
#define DD   256       // feature dim
#define M1   2049      // NQ + dustbin
#define STR  2064      // padded row stride (fp16 elems for E, bytes for E8, floats for u/v)
#define SINK_ITERS 100
#define PNWG 256       // persistent WGs (64 per batch) — <= guaranteed co-residency (256, 1/CU)
#define PTPB 1024      // 16 waves per WG

typedef __attribute__((ext_vector_type(8))) short short8;
typedef __attribute__((ext_vector_type(4))) float floatx4;
typedef __attribute__((ext_vector_type(2))) float floatx2;

__device__ __forceinline__ unsigned short f2bf(float f) {
  unsigned u = __float_as_uint(f);
  u += 0x7FFF + ((u >> 16) & 1);   // round-to-nearest-even
  return (unsigned short)(u >> 16);
}

// fp32 -> fp8 e5m2 (OCP): e5m2 == top byte of IEEE half, RN
__device__ __forceinline__ unsigned char f2fp8(float f) {
  unsigned short u = __half_as_ushort(__float2half(f));
  return (unsigned char)((u + 0x7F + ((u >> 8) & 1)) >> 8);
}

// swizzled LDS index: pad 1 float per 16 -> lane stride 17 floats (2-way = free)
__device__ __forceinline__ int IDX(int j) { return j + (j >> 4); }

// ---------------- fp32 -> bf16 convert ----------------
__global__ void k_cvt(const float* __restrict__ src, unsigned short* __restrict__ dst, int n) {
  int i = blockIdx.x * blockDim.x + threadIdx.x;
  if (i < n) dst[i] = f2bf(src[i]);
}

// ---------------- bf16 MFMA GEMM, C = A * B^T (both [rows x K] row-major) ----
// MODE 0: +bias, relu -> bf16          (MLP layer 1)
// MODE 1: +bias       -> bf16          (MLP layer 2)
// MODE 2: *1/16, clamp, exp -> fp16 AND fp8 e5m2   (scores -> E, E8)
// MODE 3: *1/16, clamp, exp -> fp8 e5m2 only       (scores -> ET8)
template<int MODE>
__global__ __launch_bounds__(256, 2)
void k_gemm_bt(const unsigned short* __restrict__ A,
               const unsigned short* __restrict__ Bt,
               void* __restrict__ Out, void* __restrict__ Out8,
               const float* __restrict__ bias,
               int K, long aBatch, long bBatch, long oBatch, int ostride)
{
  __shared__ __align__(16) unsigned short lA[128 * 32];
  __shared__ __align__(16) unsigned short lB[128 * 32];
  const int tid  = threadIdx.x;
  const int lane = tid & 63;
  const int w    = tid >> 6;
  const int wm   = (w >> 1) * 64;
  const int wn   = (w & 1) * 64;
  const long bz  = blockIdx.z;
  const unsigned short* Ab = A  + bz * aBatch + (long)blockIdx.y * 128 * K;
  const unsigned short* Bb = Bt + bz * bBatch + (long)blockIdx.x * 128 * K;

  floatx4 acc[4][4];
  #pragma unroll
  for (int i = 0; i < 4; i++)
    #pragma unroll
    for (int j = 0; j < 4; j++) acc[i][j] = (floatx4){0.f, 0.f, 0.f, 0.f};

  for (int kt = 0; kt < K; kt += 32) {
    __syncthreads();
    #pragma unroll
    for (int s0 = 0; s0 < 512; s0 += 256) {
      int s = s0 + tid;
      int row = s >> 2, part = s & 3;
      ((uint4*)lA)[s] = *(const uint4*)(Ab + (long)row * K + kt + part * 8);
      ((uint4*)lB)[s] = *(const uint4*)(Bb + (long)row * K + kt + part * 8);
    }
    __syncthreads();
    const int kq = (lane >> 4) * 8;
    const int rl = lane & 15;
    short8 af[4], bf[4];
    #pragma unroll
    for (int t = 0; t < 4; t++) {
      af[t] = *(const short8*)(lA + (wm + t * 16 + rl) * 32 + kq);
      bf[t] = *(const short8*)(lB + (wn + t * 16 + rl) * 32 + kq);
    }
    #pragma unroll
    for (int i = 0; i < 4; i++)
      #pragma unroll
      for (int j = 0; j < 4; j++)
        acc[i][j] = __builtin_amdgcn_mfma_f32_16x16x32_bf16(af[i], bf[j], acc[i][j], 0, 0, 0);
  }

  // epilogue — C/D layout: col = lane&15, row = (lane>>4)*4 + reg
  const int cl = lane & 15, qd = lane >> 4;
  #pragma unroll
  for (int i = 0; i < 4; i++)
    #pragma unroll
    for (int j = 0; j < 4; j++) {
      const int col = blockIdx.x * 128 + wn + j * 16 + cl;
      const float bcol = (MODE >= 2) ? 0.f : bias[col];
      #pragma unroll
      for (int r = 0; r < 4; r++) {
        const long row = (long)blockIdx.y * 128 + wm + i * 16 + qd * 4 + r;
        float v = acc[i][j][r];
        if (MODE == 0) {
          v += bcol; v = v > 0.f ? v : 0.f;
          ((unsigned short*)Out)[bz * oBatch + row * ostride + col] = f2bf(v);
        } else if (MODE == 1) {
          v += bcol;
          ((unsigned short*)Out)[bz * oBatch + row * ostride + col] = f2bf(v);
        } else {
          v *= 0.0625f;                       // 1/sqrt(256)
          v = fminf(fmaxf(v, -15.f), 10.9f);  // e^10.9 = 54k < e5m2 max 57344
          float e = __expf(v);
          const long idx = bz * oBatch + row * ostride + col;
          if (MODE == 2) ((__half*)Out)[idx] = __float2half(e);
          ((unsigned char*)Out8)[idx] = f2fp8(e);
        }
      }
    }
}

// ---------------- fill dustbin row/col + zero padding of fp16 E --------------
__global__ void k_fill(__half* __restrict__ E, const float* __restrict__ alphaPtr) {
  const float ea = __expf(*alphaPtr);
  const int idx = blockIdx.x * blockDim.x + threadIdx.x;
  const int n1 = NB * NQ * 16;  // rows 0..2047, cols 2048..2063
  if (idx < n1) {
    int b = idx / (NQ * 16);
    int rr = idx - b * NQ * 16;
    int i = rr >> 4;
    int j = 2048 + (rr & 15);
    E[((long)b * M1 + i) * STR + j] = (j == 2048) ? __float2half(ea) : __float2half(0.f);
  } else {
    int k = idx - n1;             // dustbin row: NB * STR entries
    if (k < NB * STR) {
      int b = k / STR;
      int j = k - b * STR;
      E[((long)b * M1 + 2048) * STR + j] = (j <= 2048) ? __float2half(ea) : __float2half(0.f);
    }
  }
}

// ---------------- init ev = 1, zero barrier flags ----------------------------
__global__ void k_init(float* __restrict__ v, int n, unsigned* __restrict__ bar) {
  int i = blockIdx.x * blockDim.x + threadIdx.x;
  if (i < n) v[i] = 1.0f;
  if (i < 2048) bar[i] = 0u;   // 4 batches x 64 flag slots (+ padding)
}

// ---------------- agent-scope relaxed helpers (NO cache invalidates) ---------
__device__ __forceinline__ void st_agent(float* p, float v) {
  __hip_atomic_store(p, v, __ATOMIC_RELAXED, __HIP_MEMORY_SCOPE_AGENT);
}
__device__ __forceinline__ void st_u32_agent(unsigned* p, unsigned v) {
  __hip_atomic_store(p, v, __ATOMIC_RELAXED, __HIP_MEMORY_SCOPE_AGENT);
}
__device__ __forceinline__ float ld_agent(const float* p) {
  return __hip_atomic_load(p, __ATOMIC_RELAXED, __HIP_MEMORY_SCOPE_AGENT);
}
__device__ __forceinline__ unsigned ld_u32_agent(const unsigned* p) {
  return __hip_atomic_load(p, __ATOMIC_RELAXED, __HIP_MEMORY_SCOPE_AGENT);
}

__device__ __forceinline__ float wave_sum(float s) {
  #pragma unroll
  for (int o = 32; o; o >>= 1) s += __shfl_xor(s, o);
  return s;
}

// dot of 16 fp8(e5m2) values with 16 fp32 weights at wp[0..15]
__device__ __forceinline__ float dot16f8(uint4 hv, const float* wp) {
  const unsigned* u = (const unsigned*)&hv;
  float s = 0.f;
#if __has_builtin(__builtin_amdgcn_cvt_pk_f32_bf8)
  #pragma unroll
  for (int q = 0; q < 4; q++) {
    floatx2 lo = __builtin_amdgcn_cvt_pk_f32_bf8((int)u[q], false);
    floatx2 hi = __builtin_amdgcn_cvt_pk_f32_bf8((int)u[q], true);
    s += lo.x * wp[q * 4 + 0] + lo.y * wp[q * 4 + 1]
       + hi.x * wp[q * 4 + 2] + hi.y * wp[q * 4 + 3];
  }
#else
  const unsigned char* p = (const unsigned char*)&hv;
  #pragma unroll
  for (int t = 0; t < 16; t++) {
    unsigned short h = (unsigned short)p[t] << 8;
    s += __half2float(*reinterpret_cast<__half*>(&h)) * wp[t];
  }
#endif
  return s;
}

// ---------------- persistent Sinkhorn, plain launch (NOT cooperative) --------
// Grid 256 WGs x 1024 thr. Co-residency guaranteed: __launch_bounds__(1024,4)
// => 1 WG/CU, capacity (256) >= grid (256); barriers cannot deadlock.
// 64 WGs per batch.
//
// R3 sync = per-WG FLAG SLOTS (no atomic contention):
//   arrive:  WG g plain-stores flags[g] = phase   (single writer per slot)
//   release: wave 0 polls all 64 flags with ONE coalesced wave load
//            (lane i reads flags[i]) + __all(f >= phase).
// Correct: flags are monotone per-slot; a WG can only store phase p+1 after
// passing barrier p, so observing all >= p implies all u-stores of phase p
// are at LLC (each WG's flag store follows its vmcnt-drained sc1 stores —
// the __syncthreads before arrive emits s_waitcnt vmcnt(0)).
// vs R0's tree: no RMW serialization, 1 LLC hop instead of 3.
//
// Rows are re-read from L2 each phase (R0 dataflow — spill-proof; the R1/R2
// register hoist spilled to scratch: WRITE_SIZE +69MB == 64 regs x 262144
// threads x 4B, +2.2GB FETCH of scratch reloads). Row loads are issued
// together with the v-staging loads so L2 latency hides under LLC latency.
// u/v traffic via agent-scope relaxed atomics (LLC-coherent, NO L2
// invalidates). Fixed 100 iterations — identical work every call.
__global__ __launch_bounds__(PTPB, 4)
void k_sink(const unsigned char* __restrict__ E8, const unsigned char* __restrict__ ET8,
            float* __restrict__ eu, float* __restrict__ ev,
            const float* __restrict__ alphaPtr, unsigned* __restrict__ bar)
{
  __shared__ __align__(16) float sv[2200];   // swizzled vector (2064 + pads)
  const int tid  = threadIdx.x;
  const int wg   = blockIdx.x;
  const int b    = wg >> 6;          // batch 0..3
  const int g    = wg & 63;          // group within batch
  const int wv   = tid >> 6;         // wave 0..15
  const int lane = tid & 63;
  const int r0   = (g * 16 + wv) * 2;   // rows r0, r0+1 in [0, 2048)
  const float ea = __expf(alphaPtr[0]);
  const unsigned char* E8r  = E8  + ((long)b * M1 + r0) * STR;
  const unsigned char* ET8r = ET8 + ((long)b * M1 + r0) * STR;
  float* ub = eu + b * STR;
  float* vb = ev + b * STR;
  unsigned* flags = bar + b * 64;    // 64 contiguous slots per batch (256 B)
  const bool dustwave = (g == 63) && (wv == 15);

  const float* w0 = sv + lane * 17;          // IDX(lane*16)
  const float* w1 = sv + 1088 + lane * 17;   // IDX(1024 + lane*16)
  const int j0 = tid;                        // [0, 1024)
  const int j1 = tid + 1024;                 // [1024, 2048)

  auto phase = [&](const unsigned char* R, const float* vin, float* vout, unsigned tgt) {
    // issue LLC v-loads and L2 row-loads together (6 loads in flight)
    float s0 = ld_agent(vin + j0);
    float s1 = ld_agent(vin + j1);
    uint4 c0 = *(const uint4*)(R +               lane * 16);
    uint4 c1 = *(const uint4*)(R + 1024 +        lane * 16);
    uint4 c2 = *(const uint4*)(R + STR  +        lane * 16);
    uint4 c3 = *(const uint4*)(R + STR  + 1024 + lane * 16);
    sv[IDX(j0)] = s0;
    sv[IDX(j1)] = s1;
    if (tid == 0) sv[IDX(2048)] = ld_agent(vin + 2048);
    __syncthreads();

    // two rows per wave
    float d0 = dot16f8(c0, w0) + dot16f8(c1, w1);
    float d1 = dot16f8(c2, w0) + dot16f8(c3, w1);
    d0 = wave_sum(d0);
    d1 = wave_sum(d1);
    if (lane == 0) {
      const float wd = ea * sv[IDX(2048)];     // dustbin column (value == ea)
      st_agent(vout + r0,     (1.f / 4096.f) / (d0 + wd));
      st_agent(vout + r0 + 1, (1.f / 4096.f) / (d1 + wd));
    }

    // dustbin row analytic: vout[2048] = 0.5 / (ea * sum(vin))
    if (dustwave) {
      float s = 0.f;
      #pragma unroll
      for (int t = 0; t < 16; t++) s += w0[t] + w1[t];
      s = wave_sum(s);
      if (lane == 0) st_agent(vout + 2048, 0.5f / (ea * (s + sv[IDX(2048)])));
    }

    // ---- per-batch flag barrier (no RMW, wave-parallel detect) ----
    __syncthreads();   // drains each wave's vmcnt: this WG's sc1 stores at LLC
    if (tid == 0) st_u32_agent(flags + g, tgt);            // arrive
    if (wv == 0) {                                         // wave 0 detects
      while (!__all((int)(ld_u32_agent(flags + lane) >= tgt)))
        __builtin_amdgcn_s_sleep(1);
    }
    __syncthreads();   // release remaining 15 waves
  };

  for (int i = 0; i < SINK_ITERS; ++i) {
    phase(E8r,  vb, ub, 2u * i + 1u);
    phase(ET8r, ub, vb, 2u * i + 2u);
  }
}

// ---------------- finalize: out = E * eu * ev * 4096 (fp16 E) ----------------
__global__ void k_final(const __half* __restrict__ E, const float* __restrict__ eu,
                        const float* __restrict__ ev, float* __restrict__ out) {
  const int wv = blockIdx.x;      // NB * M1 rows
  const int b = wv / M1;
  const int i = wv - b * M1;
  const __half* R = E + ((long)b * M1 + i) * STR;
  const float ui = eu[b * STR + i] * 4096.f;   // * exp(-norm)
  const float* evb = ev + b * STR;
  float* orow = out + ((long)b * M1 + i) * M1;
  for (int j = threadIdx.x; j < M1; j += blockDim.x)
    orow[j] = __half2float(R[j]) * ui * evb[j];
}

// ---------------- launch -----------------------------------------------------
extern "C" void kernel_launch(void* const* d_in, const int* in_sizes, int n_in,
                              void* d_out, int out_size, void* d_ws, size_t ws_size,
                              hipStream_t stream) {
  const float* x_lc  = (const float*)d_in[0];
  const float* x_te  = (const float*)d_in[1];
  const float* W1_lc = (const float*)d_in[2];
  const float* b1_lc = (const float*)d_in[3];
  const float* W2_lc = (const float*)d_in[4];
  const float* b2_lc = (const float*)d_in[5];
  const float* W1_te = (const float*)d_in[6];
  const float* b1_te = (const float*)d_in[7];
  const float* W2_te = (const float*)d_in[8];
  const float* b2_te = (const float*)d_in[9];
  const float* alpha = (const float*)d_in[10];

  char* ws = (char*)d_ws;
  unsigned short* Xlc = (unsigned short*)(ws + 0);          //  4 MB
  unsigned short* Xte = (unsigned short*)(ws + 4194304);    //  4 MB
  unsigned short* Wb  = (unsigned short*)(ws + 8388608);    //  0.5 MB
  unsigned short* H   = (unsigned short*)(ws + 8912896);    //  4 MB
  unsigned short* F1  = (unsigned short*)(ws + 13107200);   //  4 MB
  unsigned short* F2  = (unsigned short*)(ws + 17301504);   //  4 MB
  __half* E  = (__half*)(ws + 21495808);                    // 33.83 MB fp16 (final)
  unsigned char* E8  = (unsigned char*)(ws + 55328896);     // 16.92 MB fp8 (sweep)
  unsigned char* ET8 = (unsigned char*)(ws + 72245440);     // 16.92 MB fp8 (sweep)
  float* eu  = (float*)(ws + 89161984);                     // 4 x 2064 f32
  float* ev  = (float*)(ws + 89195008);                     // 4 x 2064 f32
  unsigned* bar = (unsigned*)(ws + 89228032);               // 8 KB barrier state

  const int NX = NB * NQ * DD;   // 2097152
  const int NW = DD * DD;        // 65536

  k_cvt<<<(NX + 255) / 256, 256, 0, stream>>>(x_lc, Xlc, NX);
  k_cvt<<<(NX + 255) / 256, 256, 0, stream>>>(x_te, Xte, NX);
  k_cvt<<<(NW + 255) / 256, 256, 0, stream>>>(W1_lc, Wb,           NW);
  k_cvt<<<(NW + 255) / 256, 256, 0, stream>>>(W2_lc, Wb + 65536,   NW);
  k_cvt<<<(NW + 255) / 256, 256, 0, stream>>>(W1_te, Wb + 131072,  NW);
  k_cvt<<<(NW + 255) / 256, 256, 0, stream>>>(W2_te, Wb + 196608,  NW);

  // MLPs (rows flattened over batch: M = 8192, N = 256, K = 256)
  k_gemm_bt<0><<<dim3(2, 64, 1), 256, 0, stream>>>(Xlc, Wb,          H,  nullptr, b1_lc, DD, 0, 0, 0, DD);
  k_gemm_bt<1><<<dim3(2, 64, 1), 256, 0, stream>>>(H,   Wb + 65536,  F1, nullptr, b2_lc, DD, 0, 0, 0, DD);
  k_gemm_bt<0><<<dim3(2, 64, 1), 256, 0, stream>>>(Xte, Wb + 131072, H,  nullptr, b1_te, DD, 0, 0, 0, DD);
  k_gemm_bt<1><<<dim3(2, 64, 1), 256, 0, stream>>>(H,   Wb + 196608, F2, nullptr, b2_te, DD, 0, 0, 0, DD);

  // scores -> E (fp16+fp8) and ET (fp8 only), per batch
  const long ab = (long)NQ * DD;        // 524288
  const long ob = (long)M1 * STR;       // 4229136 (elems for fp16, bytes for fp8)
  k_gemm_bt<2><<<dim3(16, 16, NB), 256, 0, stream>>>(F1, F2, E,  E8,  nullptr, DD, ab, ab, ob, STR);
  k_gemm_bt<3><<<dim3(16, 16, NB), 256, 0, stream>>>(F2, F1, nullptr, ET8, nullptr, DD, ab, ab, ob, STR);

  // dustbin row/col + padding (fp16 E only; fp8 dustbin handled analytically)
  const int nfill = NB * NQ * 16 + NB * STR;  // 139328
  k_fill<<<(nfill + 255) / 256, 256, 0, stream>>>(E, alpha);

  // ev = 1, flags = 0
  k_init<<<(NB * STR + 255) / 256, 256, 0, stream>>>(ev, NB * STR, bar);

  // persistent Sinkhorn: ONE plain launch, fixed 100 iterations
  k_sink<<<PNWG, PTPB, 0, stream>>>(E8, ET8, eu, ev, alpha, bar);

  // out = E * eu * ev * (m+n)
  k_final<<<NB * M1, 256, 0, stream>>>(E, eu, ev, (float*)d_out);
}

// Round 4
// 1090.959 us; speedup vs baseline: 2.6389x; 2.2697x over previous
//
#include <hip/hip_runtime.h>
#include <hip/hip_fp16.h>

// Problem constants
#define NQ   2048      // N_LC == N_TE
#define NB   4         // batch
#define DD   256       // feature dim
#define M1   2049      // NQ + dustbin
#define STR  2064      // padded row stride (fp16 elems for E, bytes for E8, floats for u/v)
#define SINK_ITERS 100
#define PNWG 256       // persistent WGs (64 per batch) — <= guaranteed co-residency
#define PTPB 1024      // 16 waves per WG

typedef __attribute__((ext_vector_type(8))) short short8;
typedef __attribute__((ext_vector_type(4))) float floatx4;
typedef __attribute__((ext_vector_type(2))) float floatx2;

__device__ __forceinline__ unsigned short f2bf(float f) {
  unsigned u = __float_as_uint(f);
  u += 0x7FFF + ((u >> 16) & 1);   // round-to-nearest-even
  return (unsigned short)(u >> 16);
}

// fp32 -> fp8 e5m2 (OCP): e5m2 == top byte of IEEE half, RN
__device__ __forceinline__ unsigned char f2fp8(float f) {
  unsigned short u = __half_as_ushort(__float2half(f));
  return (unsigned char)((u + 0x7F + ((u >> 8) & 1)) >> 8);
}

// swizzled LDS index: pad 1 float per 16 -> lane stride 17 floats (2-way = free)
__device__ __forceinline__ int IDX(int j) { return j + (j >> 4); }

// ---------------- merged fp32 -> bf16 convert (all 6 inputs, vec4) ----------
// total vec4 elements: 2*(NB*NQ*DD)/4 + 4*(DD*DD)/4 = 1114112 = 4352 * 256
__global__ void k_cvt6(const float* __restrict__ x_lc, const float* __restrict__ x_te,
                       const float* __restrict__ w1lc, const float* __restrict__ w2lc,
                       const float* __restrict__ w1te, const float* __restrict__ w2te,
                       unsigned short* __restrict__ Xlc, unsigned short* __restrict__ Xte,
                       unsigned short* __restrict__ Wb) {
  const int NX4 = (NB * NQ * DD) / 4;   // 524288
  const int NW4 = (DD * DD) / 4;        // 16384
  int i4 = blockIdx.x * blockDim.x + threadIdx.x;
  const float* src; unsigned short* dst; int off;
  if (i4 < NX4)            { src = x_lc; dst = Xlc; off = i4; }
  else if (i4 < 2 * NX4)   { src = x_te; dst = Xte; off = i4 - NX4; }
  else {
    int k = i4 - 2 * NX4;
    int seg = k / NW4;
    off = k - seg * NW4;
    src = (seg == 0) ? w1lc : (seg == 1) ? w2lc : (seg == 2) ? w1te : w2te;
    dst = Wb + seg * 65536;
  }
  float4 f = ((const float4*)src)[off];
  ushort4 o;
  o.x = f2bf(f.x); o.y = f2bf(f.y); o.z = f2bf(f.z); o.w = f2bf(f.w);
  ((ushort4*)dst)[off] = o;
}

// ---------------- bf16 MFMA GEMM, C = A * B^T (both [rows x K] row-major) ----
// MODE 0: +bias, relu -> bf16          (MLP layer 1)
// MODE 1: +bias       -> bf16          (MLP layer 2)
// MODE 2: *1/16, clamp, exp -> fp16 AND fp8 e5m2   (scores -> E, E8)
// MODE 3: *1/16, clamp, exp -> fp8 e5m2 only       (scores -> ET8)
template<int MODE>
__global__ __launch_bounds__(256, 2)
void k_gemm_bt(const unsigned short* __restrict__ A,
               const unsigned short* __restrict__ Bt,
               void* __restrict__ Out, void* __restrict__ Out8,
               const float* __restrict__ bias,
               int K, long aBatch, long bBatch, long oBatch, int ostride)
{
  __shared__ __align__(16) unsigned short lA[128 * 32];
  __shared__ __align__(16) unsigned short lB[128 * 32];
  const int tid  = threadIdx.x;
  const int lane = tid & 63;
  const int w    = tid >> 6;
  const int wm   = (w >> 1) * 64;
  const int wn   = (w & 1) * 64;
  const long bz  = blockIdx.z;
  const unsigned short* Ab = A  + bz * aBatch + (long)blockIdx.y * 128 * K;
  const unsigned short* Bb = Bt + bz * bBatch + (long)blockIdx.x * 128 * K;

  floatx4 acc[4][4];
  #pragma unroll
  for (int i = 0; i < 4; i++)
    #pragma unroll
    for (int j = 0; j < 4; j++) acc[i][j] = (floatx4){0.f, 0.f, 0.f, 0.f};

  for (int kt = 0; kt < K; kt += 32) {
    __syncthreads();
    #pragma unroll
    for (int s0 = 0; s0 < 512; s0 += 256) {
      int s = s0 + tid;
      int row = s >> 2, part = s & 3;
      ((uint4*)lA)[s] = *(const uint4*)(Ab + (long)row * K + kt + part * 8);
      ((uint4*)lB)[s] = *(const uint4*)(Bb + (long)row * K + kt + part * 8);
    }
    __syncthreads();
    const int kq = (lane >> 4) * 8;
    const int rl = lane & 15;
    short8 af[4], bf[4];
    #pragma unroll
    for (int t = 0; t < 4; t++) {
      af[t] = *(const short8*)(lA + (wm + t * 16 + rl) * 32 + kq);
      bf[t] = *(const short8*)(lB + (wn + t * 16 + rl) * 32 + kq);
    }
    #pragma unroll
    for (int i = 0; i < 4; i++)
      #pragma unroll
      for (int j = 0; j < 4; j++)
        acc[i][j] = __builtin_amdgcn_mfma_f32_16x16x32_bf16(af[i], bf[j], acc[i][j], 0, 0, 0);
  }

  // epilogue — C/D layout: col = lane&15, row = (lane>>4)*4 + reg
  const int cl = lane & 15, qd = lane >> 4;
  #pragma unroll
  for (int i = 0; i < 4; i++)
    #pragma unroll
    for (int j = 0; j < 4; j++) {
      const int col = blockIdx.x * 128 + wn + j * 16 + cl;
      const float bcol = (MODE >= 2) ? 0.f : bias[col];
      #pragma unroll
      for (int r = 0; r < 4; r++) {
        const long row = (long)blockIdx.y * 128 + wm + i * 16 + qd * 4 + r;
        float v = acc[i][j][r];
        if (MODE == 0) {
          v += bcol; v = v > 0.f ? v : 0.f;
          ((unsigned short*)Out)[bz * oBatch + row * ostride + col] = f2bf(v);
        } else if (MODE == 1) {
          v += bcol;
          ((unsigned short*)Out)[bz * oBatch + row * ostride + col] = f2bf(v);
        } else {
          v *= 0.0625f;                       // 1/sqrt(256)
          v = fminf(fmaxf(v, -15.f), 10.9f);  // e^10.9 = 54k < e5m2 max 57344
          float e = __expf(v);
          const long idx = bz * oBatch + row * ostride + col;
          if (MODE == 2) ((__half*)Out)[idx] = __float2half(e);
          ((unsigned char*)Out8)[idx] = f2fp8(e);
        }
      }
    }
}

// ---------------- fill dustbin row/col + zero padding of fp16 E --------------
__global__ void k_fill(__half* __restrict__ E, const float* __restrict__ alphaPtr) {
  const float ea = __expf(*alphaPtr);
  const int idx = blockIdx.x * blockDim.x + threadIdx.x;
  const int n1 = NB * NQ * 16;  // rows 0..2047, cols 2048..2063
  if (idx < n1) {
    int b = idx / (NQ * 16);
    int rr = idx - b * NQ * 16;
    int i = rr >> 4;
    int j = 2048 + (rr & 15);
    E[((long)b * M1 + i) * STR + j] = (j == 2048) ? __float2half(ea) : __float2half(0.f);
  } else {
    int k = idx - n1;             // dustbin row: NB * STR entries
    if (k < NB * STR) {
      int b = k / STR;
      int j = k - b * STR;
      E[((long)b * M1 + 2048) * STR + j] = (j <= 2048) ? __float2half(ea) : __float2half(0.f);
    }
  }
}

// ---------------- init ev = 1, zero barrier state ----------------------------
__global__ void k_init(float* __restrict__ v, int n, unsigned* __restrict__ bar) {
  int i = blockIdx.x * blockDim.x + threadIdx.x;
  if (i < n) v[i] = 1.0f;
  if (i < 2048) bar[i] = 0u;   // 4 counters used, 128 B apart
}

// ---------------- agent-scope relaxed helpers (NO cache invalidates) ---------
__device__ __forceinline__ void st_agent(float* p, float v) {
  __hip_atomic_store(p, v, __ATOMIC_RELAXED, __HIP_MEMORY_SCOPE_AGENT);
}
__device__ __forceinline__ float ld_agent(const float* p) {
  return __hip_atomic_load(p, __ATOMIC_RELAXED, __HIP_MEMORY_SCOPE_AGENT);
}
__device__ __forceinline__ unsigned ld_u32_agent(const unsigned* p) {
  return __hip_atomic_load(p, __ATOMIC_RELAXED, __HIP_MEMORY_SCOPE_AGENT);
}

__device__ __forceinline__ float wave_sum(float s) {
  #pragma unroll
  for (int o = 32; o; o >>= 1) s += __shfl_xor(s, o);
  return s;
}

// dot of 16 fp8(e5m2) values with 16 fp32 weights at wp[0..15]
__device__ __forceinline__ float dot16f8(uint4 hv, const float* wp) {
  const unsigned* u = (const unsigned*)&hv;
  float s = 0.f;
#if __has_builtin(__builtin_amdgcn_cvt_pk_f32_bf8)
  #pragma unroll
  for (int q = 0; q < 4; q++) {
    floatx2 lo = __builtin_amdgcn_cvt_pk_f32_bf8((int)u[q], false);
    floatx2 hi = __builtin_amdgcn_cvt_pk_f32_bf8((int)u[q], true);
    s += lo.x * wp[q * 4 + 0] + lo.y * wp[q * 4 + 1]
       + hi.x * wp[q * 4 + 2] + hi.y * wp[q * 4 + 3];
  }
#else
  const unsigned char* p = (const unsigned char*)&hv;
  #pragma unroll
  for (int t = 0; t < 16; t++) {
    unsigned short h = (unsigned short)p[t] << 8;
    s += __half2float(*reinterpret_cast<__half*>(&h)) * wp[t];
  }
#endif
  return s;
}

// ---------------- persistent Sinkhorn, plain launch (NOT cooperative) --------
// EXACT R0 structure (VGPR=44 codegen shape is load-bearing: no lambda, row
// loads issued AFTER the staging __syncthreads, tid0-only scalar poll).
// R1/R2/R3 rewrites all shifted codegen to VGPR=64 + scratch spill (WRITE
// +71MB, FETCH +2.2GB, 2.4ms) regardless of sync scheme — do not restructure.
//
// ONLY change vs R0: the 3-hop leaf/root/gen tree barrier is replaced by ONE
// monotone flat counter per batch. tid0: fetch_add(cnt) then poll cnt until
// >= 64*phase (same scalar-poll pattern as R0's gen poll). Monotone counter
// => correct: cnt reaches 64*(p+1) only after every WG arrived p+1 times, and
// each WG's arrival follows its vmcnt-drained sc1 stores (__syncthreads).
// Critical path: last arrival's RMW -> pollers observe (~1.5 LLC hops vs 3).
// Early arrivals' RMWs pipeline during the skew window (off critical path).
__global__ __launch_bounds__(PTPB, 4)
void k_sink(const unsigned char* __restrict__ E8, const unsigned char* __restrict__ ET8,
            float* __restrict__ eu, float* __restrict__ ev,
            const float* __restrict__ alphaPtr, unsigned* __restrict__ bar)
{
  __shared__ __align__(16) float sv[2200];   // swizzled vector (2064 + pads)
  const int tid  = threadIdx.x;
  const int wg   = blockIdx.x;
  const int b    = wg >> 6;          // batch 0..3
  const int g    = wg & 63;          // group within batch
  const int wv   = tid >> 6;         // wave 0..15
  const int lane = tid & 63;
  const int r0   = (g * 16 + wv) * 2;   // rows r0, r0+1 in [0, 2048)
  const float ea = __expf(alphaPtr[0]);
  const unsigned char* E8r  = E8  + ((long)b * M1 + r0) * STR;
  const unsigned char* ET8r = ET8 + ((long)b * M1 + r0) * STR;
  float* ub = eu + b * STR;
  float* vb = ev + b * STR;
  unsigned* cnt = bar + b * 32;      // per-batch flat counter, 128 B apart
  const bool dustwave = (g == 63) && (wv == 15);

  unsigned phase = 0;
  for (int it = 0; it < 2 * SINK_ITERS; ++it) {
    const unsigned char* R = (it & 1) ? ET8r : E8r;
    const float* vin = (it & 1) ? ub : vb;
    float*      vout = (it & 1) ? vb : ub;

    // stage vin -> swizzled LDS (sc1: fresh from LLC; 3 rounds, tid0 gets 2048)
    for (int j = tid; j < M1; j += PTPB) sv[IDX(j)] = ld_agent(vin + j);
    __syncthreads();

    // two fp8 rows per wave, 16 bytes per lane per 1024-chunk
    uint4 h0c0 = *(const uint4*)(R + lane * 16);
    uint4 h0c1 = *(const uint4*)(R + 1024 + lane * 16);
    uint4 h1c0 = *(const uint4*)(R + STR + lane * 16);
    uint4 h1c1 = *(const uint4*)(R + STR + 1024 + lane * 16);
    const float* w0 = sv + lane * 17;          // IDX(lane*16)
    const float* w1 = sv + 1088 + lane * 17;   // IDX(1024 + lane*16)
    float a0 = dot16f8(h0c0, w0) + dot16f8(h0c1, w1);
    float a1 = dot16f8(h1c0, w0) + dot16f8(h1c1, w1);
    a0 = wave_sum(a0);
    a1 = wave_sum(a1);
    if (lane == 0) {
      const float wd = ea * sv[IDX(2048)];     // dustbin column (value == ea)
      st_agent(vout + r0,     (1.f / 4096.f) / (a0 + wd));
      st_agent(vout + r0 + 1, (1.f / 4096.f) / (a1 + wd));
    }

    // dustbin row analytic: vout[2048] = 0.5 / (ea * sum(vin))
    if (dustwave) {
      float s = 0.f;
      #pragma unroll
      for (int t = 0; t < 16; t++) s += w0[t] + w1[t];
      s = wave_sum(s);
      if (lane == 0) st_agent(vout + 2048, 0.5f / (ea * (s + sv[IDX(2048)])));
    }

    // ---- per-batch flat-counter barrier (relaxed, no cache maintenance) ----
    ++phase;
    __syncthreads();   // drains vmcnt: this WG's sc1 stores are at LLC
    if (tid == 0) {
      __hip_atomic_fetch_add(cnt, 1u, __ATOMIC_RELAXED, __HIP_MEMORY_SCOPE_AGENT);
      while (ld_u32_agent(cnt) < phase * 64u)
        __builtin_amdgcn_s_sleep(1);
    }
    __syncthreads();
  }
}

// ---------------- finalize: out = E * eu * ev * 4096 (fp16 E) ----------------
__global__ void k_final(const __half* __restrict__ E, const float* __restrict__ eu,
                        const float* __restrict__ ev, float* __restrict__ out) {
  const int wv = blockIdx.x;      // NB * M1 rows
  const int b = wv / M1;
  const int i = wv - b * M1;
  const __half* R = E + ((long)b * M1 + i) * STR;
  const float ui = eu[b * STR + i] * 4096.f;   // * exp(-norm)
  const float* evb = ev + b * STR;
  float* orow = out + ((long)b * M1 + i) * M1;
  for (int j = threadIdx.x; j < M1; j += blockDim.x)
    orow[j] = __half2float(R[j]) * ui * evb[j];
}

// ---------------- launch -----------------------------------------------------
extern "C" void kernel_launch(void* const* d_in, const int* in_sizes, int n_in,
                              void* d_out, int out_size, void* d_ws, size_t ws_size,
                              hipStream_t stream) {
  const float* x_lc  = (const float*)d_in[0];
  const float* x_te  = (const float*)d_in[1];
  const float* W1_lc = (const float*)d_in[2];
  const float* b1_lc = (const float*)d_in[3];
  const float* W2_lc = (const float*)d_in[4];
  const float* b2_lc = (const float*)d_in[5];
  const float* W1_te = (const float*)d_in[6];
  const float* b1_te = (const float*)d_in[7];
  const float* W2_te = (const float*)d_in[8];
  const float* b2_te = (const float*)d_in[9];
  const float* alpha = (const float*)d_in[10];

  char* ws = (char*)d_ws;
  unsigned short* Xlc = (unsigned short*)(ws + 0);          //  4 MB
  unsigned short* Xte = (unsigned short*)(ws + 4194304);    //  4 MB
  unsigned short* Wb  = (unsigned short*)(ws + 8388608);    //  0.5 MB
  unsigned short* H   = (unsigned short*)(ws + 8912896);    //  4 MB
  unsigned short* F1  = (unsigned short*)(ws + 13107200);   //  4 MB
  unsigned short* F2  = (unsigned short*)(ws + 17301504);   //  4 MB
  __half* E  = (__half*)(ws + 21495808);                    // 33.83 MB fp16 (final)
  unsigned char* E8  = (unsigned char*)(ws + 55328896);     // 16.92 MB fp8 (sweep)
  unsigned char* ET8 = (unsigned char*)(ws + 72245440);     // 16.92 MB fp8 (sweep)
  float* eu  = (float*)(ws + 89161984);                     // 4 x 2064 f32
  float* ev  = (float*)(ws + 89195008);                     // 4 x 2064 f32
  unsigned* bar = (unsigned*)(ws + 89228032);               // 8 KB barrier state

  // merged fp32->bf16 conversion of all six inputs (one launch, vec4)
  k_cvt6<<<4352, 256, 0, stream>>>(x_lc, x_te, W1_lc, W2_lc, W1_te, W2_te,
                                   Xlc, Xte, Wb);

  // MLPs (rows flattened over batch: M = 8192, N = 256, K = 256)
  k_gemm_bt<0><<<dim3(2, 64, 1), 256, 0, stream>>>(Xlc, Wb,          H,  nullptr, b1_lc, DD, 0, 0, 0, DD);
  k_gemm_bt<1><<<dim3(2, 64, 1), 256, 0, stream>>>(H,   Wb + 65536,  F1, nullptr, b2_lc, DD, 0, 0, 0, DD);
  k_gemm_bt<0><<<dim3(2, 64, 1), 256, 0, stream>>>(Xte, Wb + 131072, H,  nullptr, b1_te, DD, 0, 0, 0, DD);
  k_gemm_bt<1><<<dim3(2, 64, 1), 256, 0, stream>>>(H,   Wb + 196608, F2, nullptr, b2_te, DD, 0, 0, 0, DD);

  // scores -> E (fp16+fp8) and ET (fp8 only), per batch
  const long ab = (long)NQ * DD;        // 524288
  const long ob = (long)M1 * STR;       // 4229136 (elems for fp16, bytes for fp8)
  k_gemm_bt<2><<<dim3(16, 16, NB), 256, 0, stream>>>(F1, F2, E,  E8,  nullptr, DD, ab, ab, ob, STR);
  k_gemm_bt<3><<<dim3(16, 16, NB), 256, 0, stream>>>(F2, F1, nullptr, ET8, nullptr, DD, ab, ab, ob, STR);

  // dustbin row/col + padding (fp16 E only; fp8 dustbin handled analytically)
  const int nfill = NB * NQ * 16 + NB * STR;  // 139328
  k_fill<<<(nfill + 255) / 256, 256, 0, stream>>>(E, alpha);

  // ev = 1, barrier = 0
  k_init<<<(NB * STR + 255) / 256, 256, 0, stream>>>(ev, NB * STR, bar);

  // persistent Sinkhorn: ONE plain launch, fixed 100 iterations
  k_sink<<<PNWG, PTPB, 0, stream>>>(E8, ET8, eu, ev, alpha, bar);

  // out = E * eu * ev * (m+n)
  k_final<<<NB * M1, 256, 0, stream>>>(E, eu, ev, (float*)d_out);
}

// Round 6
// 971.209 us; speedup vs baseline: 2.9643x; 1.1233x over previous
//
#include <hip/hip_runtime.h>
#include <hip/hip_fp16.h>

// Problem constants
#define NQ   2048      // N_LC == N_TE
#define NB   4         // batch
#define DD   256       // feature dim
#define M1   2049      // NQ + dustbin
#define STR  2064      // padded row stride (fp16 elems for E, bytes for E8, floats for u/v)
#define SINK_ITERS 100
#define PNWG 256       // persistent WGs (64 per batch) — <= guaranteed co-residency
#define PTPB 1024      // 16 waves per WG

typedef __attribute__((ext_vector_type(8))) short short8;
typedef __attribute__((ext_vector_type(4))) float floatx4;
typedef __attribute__((ext_vector_type(2))) float floatx2;

__device__ __forceinline__ unsigned short f2bf(float f) {
  unsigned u = __float_as_uint(f);
  u += 0x7FFF + ((u >> 16) & 1);   // round-to-nearest-even
  return (unsigned short)(u >> 16);
}

// fp32 -> fp8 e5m2 (OCP): e5m2 == top byte of IEEE half, RN
__device__ __forceinline__ unsigned char f2fp8(float f) {
  unsigned short u = __half_as_ushort(__float2half(f));
  return (unsigned char)((u + 0x7F + ((u >> 8) & 1)) >> 8);
}

// swizzled LDS index: pad 1 float per 16 -> lane stride 17 floats (2-way = free)
__device__ __forceinline__ int IDX(int j) { return j + (j >> 4); }

// ---------------- merged fp32 -> bf16 convert (all 6 inputs, vec4) ----------
// total vec4 elements: 2*(NB*NQ*DD)/4 + 4*(DD*DD)/4 = 1114112 = 4352 * 256
__global__ void k_cvt6(const float* __restrict__ x_lc, const float* __restrict__ x_te,
                       const float* __restrict__ w1lc, const float* __restrict__ w2lc,
                       const float* __restrict__ w1te, const float* __restrict__ w2te,
                       unsigned short* __restrict__ Xlc, unsigned short* __restrict__ Xte,
                       unsigned short* __restrict__ Wb) {
  const int NX4 = (NB * NQ * DD) / 4;   // 524288
  const int NW4 = (DD * DD) / 4;        // 16384
  int i4 = blockIdx.x * blockDim.x + threadIdx.x;
  const float* src; unsigned short* dst; int off;
  if (i4 < NX4)            { src = x_lc; dst = Xlc; off = i4; }
  else if (i4 < 2 * NX4)   { src = x_te; dst = Xte; off = i4 - NX4; }
  else {
    int k = i4 - 2 * NX4;
    int seg = k / NW4;
    off = k - seg * NW4;
    src = (seg == 0) ? w1lc : (seg == 1) ? w2lc : (seg == 2) ? w1te : w2te;
    dst = Wb + seg * 65536;
  }
  float4 f = ((const float4*)src)[off];
  ushort4 o;
  o.x = f2bf(f.x); o.y = f2bf(f.y); o.z = f2bf(f.z); o.w = f2bf(f.w);
  ((ushort4*)dst)[off] = o;
}

// ---------------- bf16 MFMA GEMM, C = A * B^T (both [rows x K] row-major) ----
// MODE 0: +bias, relu -> bf16          (MLP layer 1)
// MODE 1: +bias       -> bf16          (MLP layer 2)
// MODE 2: *1/16, clamp, exp -> fp16 AND fp8 e5m2   (scores -> E, E8)
// MODE 3: *1/16, clamp, exp -> fp8 e5m2 only       (scores -> ET8)
template<int MODE>
__global__ __launch_bounds__(256, 2)
void k_gemm_bt(const unsigned short* __restrict__ A,
               const unsigned short* __restrict__ Bt,
               void* __restrict__ Out, void* __restrict__ Out8,
               const float* __restrict__ bias,
               int K, long aBatch, long bBatch, long oBatch, int ostride)
{
  __shared__ __align__(16) unsigned short lA[128 * 32];
  __shared__ __align__(16) unsigned short lB[128 * 32];
  const int tid  = threadIdx.x;
  const int lane = tid & 63;
  const int w    = tid >> 6;
  const int wm   = (w >> 1) * 64;
  const int wn   = (w & 1) * 64;
  const long bz  = blockIdx.z;
  const unsigned short* Ab = A  + bz * aBatch + (long)blockIdx.y * 128 * K;
  const unsigned short* Bb = Bt + bz * bBatch + (long)blockIdx.x * 128 * K;

  floatx4 acc[4][4];
  #pragma unroll
  for (int i = 0; i < 4; i++)
    #pragma unroll
    for (int j = 0; j < 4; j++) acc[i][j] = (floatx4){0.f, 0.f, 0.f, 0.f};

  for (int kt = 0; kt < K; kt += 32) {
    __syncthreads();
    #pragma unroll
    for (int s0 = 0; s0 < 512; s0 += 256) {
      int s = s0 + tid;
      int row = s >> 2, part = s & 3;
      ((uint4*)lA)[s] = *(const uint4*)(Ab + (long)row * K + kt + part * 8);
      ((uint4*)lB)[s] = *(const uint4*)(Bb + (long)row * K + kt + part * 8);
    }
    __syncthreads();
    const int kq = (lane >> 4) * 8;
    const int rl = lane & 15;
    short8 af[4], bf[4];
    #pragma unroll
    for (int t = 0; t < 4; t++) {
      af[t] = *(const short8*)(lA + (wm + t * 16 + rl) * 32 + kq);
      bf[t] = *(const short8*)(lB + (wn + t * 16 + rl) * 32 + kq);
    }
    #pragma unroll
    for (int i = 0; i < 4; i++)
      #pragma unroll
      for (int j = 0; j < 4; j++)
        acc[i][j] = __builtin_amdgcn_mfma_f32_16x16x32_bf16(af[i], bf[j], acc[i][j], 0, 0, 0);
  }

  // epilogue — C/D layout: col = lane&15, row = (lane>>4)*4 + reg
  const int cl = lane & 15, qd = lane >> 4;
  #pragma unroll
  for (int i = 0; i < 4; i++)
    #pragma unroll
    for (int j = 0; j < 4; j++) {
      const int col = blockIdx.x * 128 + wn + j * 16 + cl;
      const float bcol = (MODE >= 2) ? 0.f : bias[col];
      #pragma unroll
      for (int r = 0; r < 4; r++) {
        const long row = (long)blockIdx.y * 128 + wm + i * 16 + qd * 4 + r;
        float v = acc[i][j][r];
        if (MODE == 0) {
          v += bcol; v = v > 0.f ? v : 0.f;
          ((unsigned short*)Out)[bz * oBatch + row * ostride + col] = f2bf(v);
        } else if (MODE == 1) {
          v += bcol;
          ((unsigned short*)Out)[bz * oBatch + row * ostride + col] = f2bf(v);
        } else {
          v *= 0.0625f;                       // 1/sqrt(256)
          v = fminf(fmaxf(v, -15.f), 10.9f);  // e^10.9 = 54k < e5m2 max 57344
          float e = __expf(v);
          const long idx = bz * oBatch + row * ostride + col;
          if (MODE == 2) ((__half*)Out)[idx] = __float2half(e);
          ((unsigned char*)Out8)[idx] = f2fp8(e);
        }
      }
    }
}

// ---------------- fill dustbin row/col + zero padding of fp16 E --------------
__global__ void k_fill(__half* __restrict__ E, const float* __restrict__ alphaPtr) {
  const float ea = __expf(*alphaPtr);
  const int idx = blockIdx.x * blockDim.x + threadIdx.x;
  const int n1 = NB * NQ * 16;  // rows 0..2047, cols 2048..2063
  if (idx < n1) {
    int b = idx / (NQ * 16);
    int rr = idx - b * NQ * 16;
    int i = rr >> 4;
    int j = 2048 + (rr & 15);
    E[((long)b * M1 + i) * STR + j] = (j == 2048) ? __float2half(ea) : __float2half(0.f);
  } else {
    int k = idx - n1;             // dustbin row: NB * STR entries
    if (k < NB * STR) {
      int b = k / STR;
      int j = k - b * STR;
      E[((long)b * M1 + 2048) * STR + j] = (j <= 2048) ? __float2half(ea) : __float2half(0.f);
    }
  }
}

// ---------------- init ev = 1, zero barrier state ----------------------------
__global__ void k_init(float* __restrict__ v, int n, unsigned* __restrict__ bar) {
  int i = blockIdx.x * blockDim.x + threadIdx.x;
  if (i < n) v[i] = 1.0f;
  if (i < 2048) bar[i] = 0u;   // 4 batches x {cnt, gen} on separate 128B lines
}

// ---------------- agent-scope relaxed helpers (NO cache invalidates) ---------
__device__ __forceinline__ void st_agent(float* p, float v) {
  __hip_atomic_store(p, v, __ATOMIC_RELAXED, __HIP_MEMORY_SCOPE_AGENT);
}
__device__ __forceinline__ float ld_agent(const float* p) {
  return __hip_atomic_load(p, __ATOMIC_RELAXED, __HIP_MEMORY_SCOPE_AGENT);
}
__device__ __forceinline__ unsigned ld_u32_agent(const unsigned* p) {
  return __hip_atomic_load(p, __ATOMIC_RELAXED, __HIP_MEMORY_SCOPE_AGENT);
}

__device__ __forceinline__ float wave_sum(float s) {
  #pragma unroll
  for (int o = 32; o; o >>= 1) s += __shfl_xor(s, o);
  return s;
}

// dot of 16 fp8(e5m2) values with 16 fp32 weights at wp[0..15]
__device__ __forceinline__ float dot16f8(uint4 hv, const float* wp) {
  const unsigned* u = (const unsigned*)&hv;
  float s = 0.f;
#if __has_builtin(__builtin_amdgcn_cvt_pk_f32_bf8)
  #pragma unroll
  for (int q = 0; q < 4; q++) {
    floatx2 lo = __builtin_amdgcn_cvt_pk_f32_bf8((int)u[q], false);
    floatx2 hi = __builtin_amdgcn_cvt_pk_f32_bf8((int)u[q], true);
    s += lo.x * wp[q * 4 + 0] + lo.y * wp[q * 4 + 1]
       + hi.x * wp[q * 4 + 2] + hi.y * wp[q * 4 + 3];
  }
#else
  const unsigned char* p = (const unsigned char*)&hv;
  #pragma unroll
  for (int t = 0; t < 16; t++) {
    unsigned short h = (unsigned short)p[t] << 8;
    s += __half2float(*reinterpret_cast<__half*>(&h)) * wp[t];
  }
#endif
  return s;
}

// ---------------- persistent Sinkhorn, plain launch (NOT cooperative) --------
// EXACT R0/R4 structure (VGPR=44 codegen shape is load-bearing: no lambda, row
// loads issued AFTER the staging __syncthreads, tid0-only scalar poll).
//
// R5 barrier = flat arrive + LAST-MAN BROADCAST on a SEPARATE line:
//   tid0: old = fetch_add(cnt,1)                    (arrive; pipelined RMWs)
//         if old == 64*phase-1: store gen = phase   (last arriver: free detect)
//         else: poll gen (different 128B line -> poll loads never queue behind
//               the RMW stream; R4's flat counter had pollers and RMWs
//               contending on ONE line, costing +0.19us/phase vs R0's tree)
// Correct: cnt is monotone; the 64th arrival of phase p implies every WG
// arrived p times, each after its vmcnt-drained sc1 stores (__syncthreads
// before arrive). gen=p only written by that last arriver. ~1.5 LLC hops
// after last arrival vs tree's ~2.5. Liveness: unique gen-writer per phase
// exists unconditionally; state re-zeroed by k_init before every launch.
__global__ __launch_bounds__(PTPB, 4)
void k_sink(const unsigned char* __restrict__ E8, const unsigned char* __restrict__ ET8,
            float* __restrict__ eu, float* __restrict__ ev,
            const float* __restrict__ alphaPtr, unsigned* __restrict__ bar)
{
  __shared__ __align__(16) float sv[2200];   // swizzled vector (2064 + pads)
  const int tid  = threadIdx.x;
  const int wg   = blockIdx.x;
  const int b    = wg >> 6;          // batch 0..3
  const int g    = wg & 63;          // group within batch
  const int wv   = tid >> 6;         // wave 0..15
  const int lane = tid & 63;
  const int r0   = (g * 16 + wv) * 2;   // rows r0, r0+1 in [0, 2048)
  const float ea = __expf(alphaPtr[0]);
  const unsigned char* E8r  = E8  + ((long)b * M1 + r0) * STR;
  const unsigned char* ET8r = ET8 + ((long)b * M1 + r0) * STR;
  float* ub = eu + b * STR;
  float* vb = ev + b * STR;
  unsigned* cnt = bar + b * 64;       // per-batch arrive counter
  unsigned* gen = bar + b * 64 + 32;  // release word, separate 128B line
  const bool dustwave = (g == 63) && (wv == 15);

  unsigned phase = 0;
  for (int it = 0; it < 2 * SINK_ITERS; ++it) {
    const unsigned char* R = (it & 1) ? ET8r : E8r;
    const float* vin = (it & 1) ? ub : vb;
    float*      vout = (it & 1) ? vb : ub;

    // stage vin -> swizzled LDS (sc1: fresh from LLC; 3 rounds, tid0 gets 2048)
    for (int j = tid; j < M1; j += PTPB) sv[IDX(j)] = ld_agent(vin + j);
    __syncthreads();

    // two fp8 rows per wave, 16 bytes per lane per 1024-chunk
    uint4 h0c0 = *(const uint4*)(R + lane * 16);
    uint4 h0c1 = *(const uint4*)(R + 1024 + lane * 16);
    uint4 h1c0 = *(const uint4*)(R + STR + lane * 16);
    uint4 h1c1 = *(const uint4*)(R + STR + 1024 + lane * 16);
    const float* w0 = sv + lane * 17;          // IDX(lane*16)
    const float* w1 = sv + 1088 + lane * 17;   // IDX(1024 + lane*16)
    float a0 = dot16f8(h0c0, w0) + dot16f8(h0c1, w1);
    float a1 = dot16f8(h1c0, w0) + dot16f8(h1c1, w1);
    a0 = wave_sum(a0);
    a1 = wave_sum(a1);
    if (lane == 0) {
      const float wd = ea * sv[IDX(2048)];     // dustbin column (value == ea)
      st_agent(vout + r0,     (1.f / 4096.f) / (a0 + wd));
      st_agent(vout + r0 + 1, (1.f / 4096.f) / (a1 + wd));
    }

    // dustbin row analytic: vout[2048] = 0.5 / (ea * sum(vin))
    if (dustwave) {
      float s = 0.f;
      #pragma unroll
      for (int t = 0; t < 16; t++) s += w0[t] + w1[t];
      s = wave_sum(s);
      if (lane == 0) st_agent(vout + 2048, 0.5f / (ea * (s + sv[IDX(2048)])));
    }

    // ---- per-batch barrier: flat arrive + last-man gen broadcast ----
    ++phase;
    __syncthreads();   // drains vmcnt: this WG's sc1 stores are at LLC
    if (tid == 0) {
      unsigned old = __hip_atomic_fetch_add(cnt, 1u, __ATOMIC_RELAXED, __HIP_MEMORY_SCOPE_AGENT);
      if (old == phase * 64u - 1u) {
        __hip_atomic_store(gen, phase, __ATOMIC_RELAXED, __HIP_MEMORY_SCOPE_AGENT);
      } else {
        while (ld_u32_agent(gen) < phase)
          __builtin_amdgcn_s_sleep(1);
      }
    }
    __syncthreads();
  }
}

// ---------------- finalize: out = E * eu * ev * 4096 (fp16 E) ----------------
__global__ void k_final(const __half* __restrict__ E, const float* __restrict__ eu,
                        const float* __restrict__ ev, float* __restrict__ out) {
  const int wv = blockIdx.x;      // NB * M1 rows
  const int b = wv / M1;
  const int i = wv - b * M1;
  const __half* R = E + ((long)b * M1 + i) * STR;
  const float ui = eu[b * STR + i] * 4096.f;   // * exp(-norm)
  const float* evb = ev + b * STR;
  float* orow = out + ((long)b * M1 + i) * M1;
  for (int j = threadIdx.x; j < M1; j += blockDim.x)
    orow[j] = __half2float(R[j]) * ui * evb[j];
}

// ---------------- launch -----------------------------------------------------
extern "C" void kernel_launch(void* const* d_in, const int* in_sizes, int n_in,
                              void* d_out, int out_size, void* d_ws, size_t ws_size,
                              hipStream_t stream) {
  const float* x_lc  = (const float*)d_in[0];
  const float* x_te  = (const float*)d_in[1];
  const float* W1_lc = (const float*)d_in[2];
  const float* b1_lc = (const float*)d_in[3];
  const float* W2_lc = (const float*)d_in[4];
  const float* b2_lc = (const float*)d_in[5];
  const float* W1_te = (const float*)d_in[6];
  const float* b1_te = (const float*)d_in[7];
  const float* W2_te = (const float*)d_in[8];
  const float* b2_te = (const float*)d_in[9];
  const float* alpha = (const float*)d_in[10];

  char* ws = (char*)d_ws;
  unsigned short* Xlc = (unsigned short*)(ws + 0);          //  4 MB
  unsigned short* Xte = (unsigned short*)(ws + 4194304);    //  4 MB
  unsigned short* Wb  = (unsigned short*)(ws + 8388608);    //  0.5 MB
  unsigned short* H   = (unsigned short*)(ws + 8912896);    //  4 MB
  unsigned short* F1  = (unsigned short*)(ws + 13107200);   //  4 MB
  unsigned short* F2  = (unsigned short*)(ws + 17301504);   //  4 MB
  __half* E  = (__half*)(ws + 21495808);                    // 33.83 MB fp16 (final)
  unsigned char* E8  = (unsigned char*)(ws + 55328896);     // 16.92 MB fp8 (sweep)
  unsigned char* ET8 = (unsigned char*)(ws + 72245440);     // 16.92 MB fp8 (sweep)
  float* eu  = (float*)(ws + 89161984);                     // 4 x 2064 f32
  float* ev  = (float*)(ws + 89195008);                     // 4 x 2064 f32
  unsigned* bar = (unsigned*)(ws + 89228032);               // 8 KB barrier state

  // merged fp32->bf16 conversion of all six inputs (one launch, vec4)
  k_cvt6<<<4352, 256, 0, stream>>>(x_lc, x_te, W1_lc, W2_lc, W1_te, W2_te,
                                   Xlc, Xte, Wb);

  // MLPs (rows flattened over batch: M = 8192, N = 256, K = 256)
  k_gemm_bt<0><<<dim3(2, 64, 1), 256, 0, stream>>>(Xlc, Wb,          H,  nullptr, b1_lc, DD, 0, 0, 0, DD);
  k_gemm_bt<1><<<dim3(2, 64, 1), 256, 0, stream>>>(H,   Wb + 65536,  F1, nullptr, b2_lc, DD, 0, 0, 0, DD);
  k_gemm_bt<0><<<dim3(2, 64, 1), 256, 0, stream>>>(Xte, Wb + 131072, H,  nullptr, b1_te, DD, 0, 0, 0, DD);
  k_gemm_bt<1><<<dim3(2, 64, 1), 256, 0, stream>>>(H,   Wb + 196608, F2, nullptr, b2_te, DD, 0, 0, 0, DD);

  // scores -> E (fp16+fp8) and ET (fp8 only), per batch
  const long ab = (long)NQ * DD;        // 524288
  const long ob = (long)M1 * STR;       // 4229136 (elems for fp16, bytes for fp8)
  k_gemm_bt<2><<<dim3(16, 16, NB), 256, 0, stream>>>(F1, F2, E,  E8,  nullptr, DD, ab, ab, ob, STR);
  k_gemm_bt<3><<<dim3(16, 16, NB), 256, 0, stream>>>(F2, F1, nullptr, ET8, nullptr, DD, ab, ab, ob, STR);

  // dustbin row/col + padding (fp16 E only; fp8 dustbin handled analytically)
  const int nfill = NB * NQ * 16 + NB * STR;  // 139328
  k_fill<<<(nfill + 255) / 256, 256, 0, stream>>>(E, alpha);

  // ev = 1, barrier = 0
  k_init<<<(NB * STR + 255) / 256, 256, 0, stream>>>(ev, NB * STR, bar);

  // persistent Sinkhorn: ONE plain launch, fixed 100 iterations
  k_sink<<<PNWG, PTPB, 0, stream>>>(E8, ET8, eu, ev, alpha, bar);

  // out = E * eu * ev * (m+n)
  k_final<<<NB * M1, 256, 0, stream>>>(E, eu, ev, (float*)d_out);
}